// Round 6
// baseline (456.056 us; speedup 1.0000x reference)
//
#include <hip/hip_runtime.h>

// ============================================================================
// PlasticityModelMoE — MI355X (gfx950). Inputs f32, output f32, bf16 MFMA.
// R13:
//  (a) 8-phase core -> 6-phase: B n2-3 read hoisted into ph1; ph2+ph3 merge
//      into one 32-MFMA pure-register cluster (af03/af47/bfr01/bfr23 all
//      live). Barriers 7 -> 5 per tile. Identical accumulation order.
//      Cross-wave safety: reads of buf end at ph1 (lgkm-retired before its
//      MFMA); staging targets buf^1; tile-end vmcnt(0)+barrier unchanged.
//  (b) launch fusion: k_prep = small ∥ gate_y ∥ wmT (block-role partition;
//      k_small's serial block hides under BW roles); k_post = softmax ∥
//      transpose(mem). 13 -> 8 launches. transpose(rW) stays standalone
//      (ordered after reduce_blend: rwT region aliases A-partials).
// ============================================================================

typedef unsigned short u16;
typedef __attribute__((ext_vector_type(8))) short bf16x8;   // 8 bf16 = 4 VGPRs
typedef __attribute__((ext_vector_type(4))) float f32x4;

__device__ __forceinline__ float b2f(u16 h) {
    union { unsigned u; float f; } v; v.u = ((unsigned)h) << 16; return v.f;
}
__device__ __forceinline__ u16 f2b(float f) {
    union { float f; unsigned u; } v; v.f = f;
    unsigned u = v.u;
    return (u16)((u + 0x7fffu + ((u >> 16) & 1u)) >> 16);   // round-nearest-even
}

// async global->LDS, 16B per lane (wave-uniform base + lane*16 — m97 pattern).
__device__ __forceinline__ void async_copy16(void* lds, const void* g) {
    __builtin_amdgcn_global_load_lds(
        (__attribute__((address_space(1))) void*)(g),
        (__attribute__((address_space(3))) void*)(lds), 16, 0, 0);
}

// 3-bit swizzle for 128B-row tiles: 16B-slot bits [6:4] ^= row bits [9:7].
// Involution; conflict-free ds_read_b128 (R11: BANK_CONFLICT -> 0).
__device__ __forceinline__ int swz(int o) { return o ^ (((o >> 7) & 7) << 4); }

// 2-bit swizzle for 64B-row tiles (2-phase core): slot ^= row&3. 8way->4way.
__device__ __forceinline__ int swz64(int kg, int row) { return kg ^ (row & 3); }

// ---------------------------------------------------------------------------
// 256x256 6-phase GEMM core (T2+T3+T4+T5). C[256,256] = A[256,K]*B[256,K]^T.
// 512 thr / 8 waves as 2(M) x 4(N); per-wave 128x64; acc[8][4] f32x4.
// lds: 128 KiB = 2 bufs x { A: 2x(128x64) halves, B: same } bf16, swizzled.
// Ktiles = K/64 (>=2). ld = row stride of A and B in elements.
// ---------------------------------------------------------------------------
__device__ __forceinline__ void stage_tile256(const u16* __restrict__ src, int ld,
                                              int base0, int k0,
                                              char* ldsbase, int tid)
{
#pragma unroll
    for (int h = 0; h < 2; h++)
#pragma unroll
        for (int it = 0; it < 2; it++) {
            int o = it * 8192 + tid * 16;          // linear LDS byte offset
            int s = swz(o);                        // logical source offset
            int r = s >> 7;                        // row within 128-row half
            int c = (s & 127) >> 1;                // bf16 col (multiple of 8)
            async_copy16(ldsbase + h * 16384 + o,
                         src + (size_t)(base0 + h * 128 + r) * ld + k0 + c);
        }
}

__device__ __forceinline__ void gemm256_core8(const u16* __restrict__ A,
                                              const u16* __restrict__ B,
                                              int Ktiles, int ld,
                                              int row0, int col0,
                                              char* lds, f32x4 (&acc)[8][4])
{
    const int tid  = threadIdx.x;
    const int lane = tid & 63;
    const int wv   = tid >> 6;
    const int wr   = wv >> 2;          // 0..1  (M half)
    const int wc   = wv & 3;           // 0..3  (N quarter)
    const int lr   = lane & 15, kg = lane >> 4;

#pragma unroll
    for (int i = 0; i < 8; i++)
#pragma unroll
        for (int j = 0; j < 4; j++) {
            f32x4 z = {0.f, 0.f, 0.f, 0.f};
            acc[i][j] = z;
        }

    // prologue: stage tile 0 into buf 0
    stage_tile256(A, ld, row0, 0, lds, tid);
    stage_tile256(B, ld, col0, 0, lds + 32768, tid);
    asm volatile("s_waitcnt vmcnt(0)" ::: "memory");
    __builtin_amdgcn_s_barrier();

    bf16x8 af03[4][2], af47[4][2], b01[2][2], b23[2][2];

    for (int t = 0; t < Ktiles; t++) {
        const int buf = (t & 1) << 16;
        const char* sA = lds + buf + wr * 16384;
        const char* sB = lds + buf + 32768 + ((wc >> 1) * 16384);
        char* nb = lds + (((t + 1) & 1) << 16);
        const bool pf = (t + 1 < Ktiles);

        auto rdA = [&](int i, int ks) {
            int off = (i * 16 + lr) * 128 + ks * 64 + kg * 16;
            return *(const bf16x8*)(sA + swz(off));
        };
        auto rdB = [&](int j, int ks) {
            int off = ((wc & 1) * 64 + j * 16 + lr) * 128 + ks * 64 + kg * 16;
            return *(const bf16x8*)(sB + swz(off));
        };

        // ---- phase 0: read A m0-3 + B n0-1; stage A(t+1); MFMA m0-3 x n0-1
#pragma unroll
        for (int i = 0; i < 4; i++) { af03[i][0] = rdA(i, 0); af03[i][1] = rdA(i, 1); }
#pragma unroll
        for (int j = 0; j < 2; j++) { b01[j][0] = rdB(j, 0); b01[j][1] = rdB(j, 1); }
        if (pf) stage_tile256(A, ld, row0, (t + 1) * 64, nb, tid);
        __builtin_amdgcn_s_barrier();
        __builtin_amdgcn_s_setprio(1);
#pragma unroll
        for (int i = 0; i < 4; i++)
#pragma unroll
            for (int j = 0; j < 2; j++) {
                acc[i][j] = __builtin_amdgcn_mfma_f32_16x16x32_bf16(af03[i][0], b01[j][0], acc[i][j], 0, 0, 0);
                acc[i][j] = __builtin_amdgcn_mfma_f32_16x16x32_bf16(af03[i][1], b01[j][1], acc[i][j], 0, 0, 0);
            }
        __builtin_amdgcn_s_setprio(0);
        __builtin_amdgcn_s_barrier();

        // ---- phase 1: read A m4-7 + B n2-3; stage B(t+1); MFMA m4-7 x n0-1
#pragma unroll
        for (int i = 0; i < 4; i++) { af47[i][0] = rdA(4 + i, 0); af47[i][1] = rdA(4 + i, 1); }
#pragma unroll
        for (int j = 0; j < 2; j++) { b23[j][0] = rdB(2 + j, 0); b23[j][1] = rdB(2 + j, 1); }
        if (pf) stage_tile256(B, ld, col0, (t + 1) * 64, nb + 32768, tid);
        __builtin_amdgcn_s_barrier();
        __builtin_amdgcn_s_setprio(1);
#pragma unroll
        for (int i = 0; i < 4; i++)
#pragma unroll
            for (int j = 0; j < 2; j++) {
                acc[4 + i][j] = __builtin_amdgcn_mfma_f32_16x16x32_bf16(af47[i][0], b01[j][0], acc[4 + i][j], 0, 0, 0);
                acc[4 + i][j] = __builtin_amdgcn_mfma_f32_16x16x32_bf16(af47[i][1], b01[j][1], acc[4 + i][j], 0, 0, 0);
            }
        __builtin_amdgcn_s_setprio(0);
        __builtin_amdgcn_s_barrier();

        // ---- phase 2+3 merged: pure-register 32-MFMA cluster (no LDS, no
        //      barriers): m4-7 x n2-3 then m0-3 x n2-3 ----
        __builtin_amdgcn_s_setprio(1);
#pragma unroll
        for (int i = 0; i < 4; i++)
#pragma unroll
            for (int j = 0; j < 2; j++) {
                acc[4 + i][2 + j] = __builtin_amdgcn_mfma_f32_16x16x32_bf16(af47[i][0], b23[j][0], acc[4 + i][2 + j], 0, 0, 0);
                acc[4 + i][2 + j] = __builtin_amdgcn_mfma_f32_16x16x32_bf16(af47[i][1], b23[j][1], acc[4 + i][2 + j], 0, 0, 0);
            }
#pragma unroll
        for (int i = 0; i < 4; i++)
#pragma unroll
            for (int j = 0; j < 2; j++) {
                acc[i][2 + j] = __builtin_amdgcn_mfma_f32_16x16x32_bf16(af03[i][0], b23[j][0], acc[i][2 + j], 0, 0, 0);
                acc[i][2 + j] = __builtin_amdgcn_mfma_f32_16x16x32_bf16(af03[i][1], b23[j][1], acc[i][2 + j], 0, 0, 0);
            }
        __builtin_amdgcn_s_setprio(0);
        // tile boundary: staging loads (issued >=2 phases ago) must land
        asm volatile("s_waitcnt vmcnt(0)" ::: "memory");
        __builtin_amdgcn_s_barrier();
    }
}

// ---------------------------------------------------------------------------
// Double-buffered 2-phase GEMM core — used by GEMM-C. S windows of BK=32;
// 64B-row LDS; 2-bit slot swizzle (slot ^= row&3) on both sides.
// ---------------------------------------------------------------------------
template<int BM, int BN, int S>
__device__ __forceinline__ void gemm_core_db(const u16* __restrict__ A,
                                             const u16* __restrict__ B,
                                             int Kloop, int ld,
                                             int row0, int col0,
                                             u16* smem,
                                             f32x4 (&acc)[BM / 32][BN / 32])
{
    constexpr int MT = BM / 32, NT = BN / 32;
    constexpr int STG = (BM + BN) * 32;     // u16 per stage
    constexpr int SET = STG * S;            // u16 per buffer set
    const int tid  = threadIdx.x;
    const int lane = tid & 63;
    const int wv   = tid >> 6;
    const int wr   = wv >> 1, wc = wv & 1;
    const int lr   = lane & 15, kg = lane >> 4;

#pragma unroll
    for (int i = 0; i < MT; i++)
#pragma unroll
        for (int j = 0; j < NT; j++) {
            f32x4 z = {0.f, 0.f, 0.f, 0.f};
            acc[i][j] = z;
        }

    auto stage_in = [&](u16* set, int k0) {
#pragma unroll
        for (int c = tid; c < BM * 4; c += 256) {
            int row = c >> 2, sl = swz64(c & 3, row);
            const u16* gA = A + (size_t)(row0 + row) * ld + k0 + sl * 8;
#pragma unroll
            for (int s = 0; s < S; s++)
                async_copy16(set + s * STG + c * 8, gA + s * 32);
        }
#pragma unroll
        for (int c = tid; c < BN * 4; c += 256) {
            int row = c >> 2, sl = swz64(c & 3, row);
            const u16* gB = B + (size_t)(col0 + row) * ld + k0 + sl * 8;
#pragma unroll
            for (int s = 0; s < S; s++)
                async_copy16(set + s * STG + BM * 32 + c * 8, gB + s * 32);
        }
    };

    stage_in(smem, 0);
    __syncthreads();           // drain prologue staging

    int p = 0;
    for (int k0 = 0; k0 < Kloop; k0 += 32 * S) {
        if (k0 + 32 * S < Kloop)
            stage_in(smem + (p ^ 1) * SET, k0 + 32 * S);   // prefetch next window
        u16* set = smem + p * SET;
#pragma unroll
        for (int s = 0; s < S; s++) {
            const u16* sA = set + s * STG;
            const u16* sB = sA + BM * 32;
            bf16x8 af[MT], bfr[NT];
#pragma unroll
            for (int i = 0; i < MT; i++) {
                int row = wr * (BM / 2) + i * 16 + lr;
                af[i] = *(const bf16x8*)(sA + (row * 32 + swz64(kg, row) * 8));
            }
#pragma unroll
            for (int j = 0; j < NT; j++) {
                int row = wc * (BN / 2) + j * 16 + lr;
                bfr[j] = *(const bf16x8*)(sB + (row * 32 + swz64(kg, row) * 8));
            }
#pragma unroll
            for (int i = 0; i < MT; i++)
#pragma unroll
                for (int j = 0; j < NT; j++)
                    acc[i][j] = __builtin_amdgcn_mfma_f32_16x16x32_bf16(
                                    af[i], bfr[j], acc[i][j], 0, 0, 0);
        }
        __syncthreads();       // one barrier/window; vmcnt drain overlapped above
        p ^= 1;
    }
}

// ---------------------------------------------------------------------------
// k_prep: fused independent pre-GEMM work, block-role partitioned.
//   block 0       : conn = sigmoid(relu(na@W1+b1)@W2+b2); wts = softmax(act_w)
//   blocks 1-512  : gate softmax + y = x*gate (bf16)
//   blocks 513-1536: wmT[u, d*4+b] = w[d,u,b]*sigmoid(delay[d,u,b]) (bf16)
// ---------------------------------------------------------------------------
__global__ __launch_bounds__(256)
void k_prep(const float* __restrict__ na, const float* __restrict__ W1,
            const float* __restrict__ b1, const float* __restrict__ W2,
            const float* __restrict__ b2, const float* __restrict__ actw,
            float* __restrict__ conn, float* __restrict__ wts,
            const float* __restrict__ x, const float* __restrict__ gW,
            const float* __restrict__ gb, float* __restrict__ gate,
            u16* __restrict__ y,
            const float* __restrict__ w, const float* __restrict__ delay,
            u16* __restrict__ wmT)
{
    __shared__ __align__(16) char sh[256 * 32 * 4 + 128];
    const int bid = blockIdx.x;
    const int tid = threadIdx.x;

    if (bid == 0) {
        // ---- role: small MLP + act-weight softmax ----
        float* red = (float*)sh;
        float* hsh = (float*)(sh + 256 * 32 * 4);
        float h[32];
#pragma unroll
        for (int k = 0; k < 32; k++) h[k] = 0.f;
        for (int u = tid; u < 2048; u += 256) {
            float nav = na[u];
            const float* row = W1 + u * 32;
#pragma unroll
            for (int k = 0; k < 32; k++) h[k] += nav * row[k];
        }
#pragma unroll
        for (int k = 0; k < 32; k++) red[tid * 32 + k] = h[k];
        for (int s = 128; s > 0; s >>= 1) {
            __syncthreads();
            if (tid < s)
#pragma unroll
                for (int k = 0; k < 32; k++) red[tid * 32 + k] += red[(tid + s) * 32 + k];
        }
        __syncthreads();
        if (tid < 32) hsh[tid] = fmaxf(red[tid] + b1[tid], 0.f);
        if (tid == 0) {
            float e[9], m = -1e30f;
            for (int i = 0; i < 9; i++) { e[i] = actw[i]; m = fmaxf(m, e[i]); }
            float s = 0.f;
            for (int i = 0; i < 9; i++) { e[i] = expf(e[i] - m); s += e[i]; }
            for (int i = 0; i < 9; i++) wts[i] = e[i] / s;
        }
        __syncthreads();
        for (int u = tid; u < 2048; u += 256) {
            float a = 0.f;
#pragma unroll
            for (int k = 0; k < 32; k++) a += hsh[k] * W2[k * 2048 + u];
            conn[u] = 1.f / (1.f + expf(-(a + b2[u])));
        }
    } else if (bid <= 512) {
        // ---- role: gate softmax + y = x*gate ----
        const int lane = tid & 63, wvx = tid >> 6;
        const int n = (bid - 1) * 4 + wvx;
        const float* xr = x + (size_t)n * 1024;
        float a0 = 0, a1 = 0, a2 = 0, a3 = 0;
        float xv[16];
#pragma unroll
        for (int s = 0; s < 16; s++) {
            int d = s * 64 + lane;
            float xd = xr[d]; xv[s] = xd;
            float4 g4 = *(const float4*)(gW + d * 4);
            a0 += xd * g4.x; a1 += xd * g4.y; a2 += xd * g4.z; a3 += xd * g4.w;
        }
#pragma unroll
        for (int off = 32; off > 0; off >>= 1) {
            a0 += __shfl_xor(a0, off); a1 += __shfl_xor(a1, off);
            a2 += __shfl_xor(a2, off); a3 += __shfl_xor(a3, off);
        }
        a0 += gb[0]; a1 += gb[1]; a2 += gb[2]; a3 += gb[3];
        float m = fmaxf(fmaxf(a0, a1), fmaxf(a2, a3));
        float e0 = expf(a0 - m), e1 = expf(a1 - m), e2 = expf(a2 - m), e3 = expf(a3 - m);
        float inv = 1.f / (e0 + e1 + e2 + e3);
        float g0 = e0 * inv, g1 = e1 * inv, g2 = e2 * inv, g3 = e3 * inv;
        if (lane == 0) *(float4*)(gate + n * 4) = make_float4(g0, g1, g2, g3);
#pragma unroll
        for (int s = 0; s < 16; s++) {
            int d = s * 64 + lane;
            ushort4 o;
            o.x = f2b(xv[s] * g0); o.y = f2b(xv[s] * g1);
            o.z = f2b(xv[s] * g2); o.w = f2b(xv[s] * g3);
            *(ushort4*)(y + (size_t)n * 4096 + d * 4) = o;
        }
    } else {
        // ---- role: wmT transpose+cast ----
        typedef ushort4 row65[65];
        row65* tile = (row65*)sh;
        const int b = bid - 513;
        const int u0 = (b & 31) * 64, d0 = (b >> 5) * 32;
        const int tx = tid & 63, ty = tid >> 6;
#pragma unroll
        for (int i = 0; i < 8; i++) {
            int d = i * 4 + ty;
            size_t idx = ((size_t)(d0 + d) * 2048 + (u0 + tx)) * 4;
            float4 w4 = *(const float4*)(w + idx);
            float4 d4 = *(const float4*)(delay + idx);
            ushort4 o;
            o.x = f2b(w4.x / (1.f + expf(-d4.x)));
            o.y = f2b(w4.y / (1.f + expf(-d4.y)));
            o.z = f2b(w4.z / (1.f + expf(-d4.z)));
            o.w = f2b(w4.w / (1.f + expf(-d4.w)));
            tile[d][tx] = o;
        }
        __syncthreads();
        const int dx = tid & 31, uy = tid >> 5;
#pragma unroll
        for (int i = 0; i < 8; i++) {
            int u = i * 8 + uy;
            *(ushort4*)(wmT + (size_t)(u0 + u) * 4096 + (d0 + dx) * 4) = tile[dx][u];
        }
    }
}

// ---------------------------------------------------------------------------
// transpose + cast: in[R,C] f32 -> out[C,R] bf16, 64x64 tiles (rW only)
// ---------------------------------------------------------------------------
__global__ __launch_bounds__(256)
void k_transpose(const float* __restrict__ in, u16* __restrict__ out, int R, int C)
{
    __shared__ __align__(16) u16 t[64][68];
    const int tid = threadIdx.x, tx = tid & 15, ty = tid >> 4;
    const int c0 = blockIdx.x * 64, r0 = blockIdx.y * 64;
#pragma unroll
    for (int i = 0; i < 4; i++) {
        int r = r0 + ty + i * 16;
        float4 v = *(const float4*)(in + (size_t)r * C + c0 + tx * 4);
        t[tx * 4 + 0][ty + i * 16] = f2b(v.x); t[tx * 4 + 1][ty + i * 16] = f2b(v.y);
        t[tx * 4 + 2][ty + i * 16] = f2b(v.z); t[tx * 4 + 3][ty + i * 16] = f2b(v.w);
    }
    __syncthreads();
#pragma unroll
    for (int i = 0; i < 4; i++) {
        int c = ty + i * 16;
        ushort4 v;
        v.x = t[c][tx * 4 + 0]; v.y = t[c][tx * 4 + 1];
        v.z = t[c][tx * 4 + 2]; v.w = t[c][tx * 4 + 3];
        *(ushort4*)(out + (size_t)(c0 + c) * R + r0 + tx * 4) = v;
    }
}

// ---------------------------------------------------------------------------
// 8-way activation blend
// ---------------------------------------------------------------------------
__device__ __forceinline__ float act_blend(float a,
    float w0, float w1, float w2, float w3,
    float w4, float w5, float w6, float w7)
{
    float sig = 1.f / (1.f + expf(-a));
    float elu = (a > 0.f) ? a : (expf(a) - 1.f);
    float th  = tanhf(a);
    float rel = fmaxf(a, 0.f);
    float sil = a * sig;
    float gel = a * 0.5f * (1.f + erff(a * 0.70710678118654752f));
    float sel = (a > 0.f) ? 1.0507009873554805f * a
                          : 1.0507009873554805f * 1.6732632423543772f * (expf(a) - 1.f);
    float sp  = (a > 20.f) ? a : log1pf(expf(a));
    float mish = a * tanhf(sp);
    return w0 * sig + w1 * elu + w2 * th + w3 * rel + w4 * sil + w5 * gel
         + w6 * sel + w7 * mish;
}

// ---------------------------------------------------------------------------
// GEMM-A (6-phase 256^2, split-K): P[z][n,u] partial = y@wmT^T over K-chunk z.
// grid (8, 8, 4), 512 thr, LDS 128 KiB -> 256 blocks, 1/CU.
// ---------------------------------------------------------------------------
__global__ __launch_bounds__(512, 2)
void k_gemm_a8(const u16* __restrict__ A, const u16* __restrict__ B,
               float* __restrict__ P)
{
    __shared__ __align__(16) char lds[131072];
    const int row0 = blockIdx.y * 256, col0 = blockIdx.x * 256;
    const u16* Ac = A + (size_t)blockIdx.z * 1024;
    const u16* Bc = B + (size_t)blockIdx.z * 1024;

    f32x4 acc[8][4];
    gemm256_core8(Ac, Bc, 16, 4096, row0, col0, lds, acc);

    float* Pz = P + (size_t)blockIdx.z * 2048 * 2048;
    const int tid = threadIdx.x, lane = tid & 63, wv = tid >> 6;
    const int wr = wv >> 2, wc = wv & 3, lr = lane & 15, kg = lane >> 4;
#pragma unroll
    for (int i = 0; i < 8; i++)
#pragma unroll
        for (int r = 0; r < 4; r++) {
            int n = row0 + wr * 128 + i * 16 + kg * 4 + r;
            size_t ob = (size_t)n * 2048;
#pragma unroll
            for (int j = 0; j < 4; j++)
                Pz[ob + col0 + wc * 64 + j * 16 + lr] = acc[i][j][r];
        }
}

// ---------------------------------------------------------------------------
// reduce 4 split-K partials + GEMM-A epilogue:
// blend[n,u] = blend8(relu((sum_s P[s][n,u] + gate[n]·b[u])*conn[u]*mask[u]))
// ---------------------------------------------------------------------------
__global__ __launch_bounds__(256)
void k_reduce_blend(const float* __restrict__ P, const float* __restrict__ gate,
                    const float* __restrict__ conn, const float* __restrict__ mask,
                    const float* __restrict__ wts, const float* __restrict__ bbias,
                    u16* __restrict__ blend)
{
    constexpr size_t SL = (size_t)2048 * 2048;
    const int n  = blockIdx.x;
    const int u0 = threadIdx.x * 8;
    const float* base = P + (size_t)n * 2048 + u0;

    float v[8];
#pragma unroll
    for (int h = 0; h < 2; h++) {
        float4 a = *(const float4*)(base + h * 4);
        float4 b = *(const float4*)(base + SL + h * 4);
        float4 c = *(const float4*)(base + 2 * SL + h * 4);
        float4 d = *(const float4*)(base + 3 * SL + h * 4);
        v[h * 4 + 0] = a.x + b.x + c.x + d.x;
        v[h * 4 + 1] = a.y + b.y + c.y + d.y;
        v[h * 4 + 2] = a.z + b.z + c.z + d.z;
        v[h * 4 + 3] = a.w + b.w + c.w + d.w;
    }
    float4 g = *(const float4*)(gate + n * 4);
    const float w0 = wts[0], w1 = wts[1], w2 = wts[2], w3 = wts[3];
    const float w4 = wts[4], w5 = wts[5], w6 = wts[6], w7 = wts[7];

    ushort4 o[2];
#pragma unroll
    for (int j = 0; j < 8; j++) {
        int u = u0 + j;
        float4 b4 = *(const float4*)(bbias + u * 4);
        float z = v[j] + g.x * b4.x + g.y * b4.y + g.z * b4.z + g.w * b4.w;
        float a = fmaxf(z * conn[u] * mask[u], 0.f);
        u16 r = f2b(act_blend(a, w0, w1, w2, w3, w4, w5, w6, w7));
        ((u16*)o)[j] = r;
    }
    *(ushort4*)(blend + (size_t)n * 2048 + u0)     = o[0];
    *(ushort4*)(blend + (size_t)n * 2048 + u0 + 4) = o[1];
}

// ---------------------------------------------------------------------------
// GEMM-B (6-phase 256^2): logits[n,m] = blend@read_W^T + read_b (bf16 out)
// grid (32, 8), 512 thr -> 256 blocks, 1/CU.
// ---------------------------------------------------------------------------
__global__ __launch_bounds__(512, 2)
void k_gemm_logits8(const u16* __restrict__ BL, const u16* __restrict__ RWT,
                    const float* __restrict__ rbias, u16* __restrict__ out)
{
    __shared__ __align__(16) char lds[131072];
    const int row0 = blockIdx.y * 256, col0 = blockIdx.x * 256;

    f32x4 acc[8][4];
    gemm256_core8(BL, RWT, 32, 2048, row0, col0, lds, acc);

    const int tid = threadIdx.x, lane = tid & 63, wv = tid >> 6;
    const int wr = wv >> 2, wc = wv & 3, lr = lane & 15, kg = lane >> 4;
    float rb[4]; int mm[4];
#pragma unroll
    for (int j = 0; j < 4; j++) {
        mm[j] = col0 + wc * 64 + j * 16 + lr;
        rb[j] = rbias[mm[j]];
    }
#pragma unroll
    for (int i = 0; i < 8; i++)
#pragma unroll
        for (int r = 0; r < 4; r++) {
            int n = row0 + wr * 128 + i * 16 + kg * 4 + r;
            size_t ob = (size_t)n * 8192;
#pragma unroll
            for (int j = 0; j < 4; j++)
                out[ob + mm[j]] = f2b(acc[i][j][r] + rb[j]);
        }
}

// ---------------------------------------------------------------------------
// k_post: fused softmax(logits) ∥ transpose(mem -> memT).
//   blocks 0-2047   : in-place row softmax over 8192 bf16
//   blocks 2048-4095: mem[8192,1024] f32 -> memT[1024,8192] bf16
// ---------------------------------------------------------------------------
__global__ __launch_bounds__(256)
void k_post(u16* __restrict__ buf, const float* __restrict__ mem,
            u16* __restrict__ memT)
{
    __shared__ __align__(16) char sh[64 * 68 * 2 + 64];
    const int bid = blockIdx.x;
    const int tid = threadIdx.x;

    if (bid < 2048) {
        float* red = (float*)sh;
        const int lane = tid & 63, wv = tid >> 6;
        u16* row = buf + (size_t)bid * 8192;
        float v[32];
        float mx = -1e30f;
#pragma unroll
        for (int s = 0; s < 8; s++) {
            ushort4 u4 = *(const ushort4*)(row + (s * 256 + tid) * 4);
            float a = b2f(u4.x), b = b2f(u4.y), c = b2f(u4.z), d = b2f(u4.w);
            v[s * 4 + 0] = a; v[s * 4 + 1] = b; v[s * 4 + 2] = c; v[s * 4 + 3] = d;
            mx = fmaxf(mx, fmaxf(fmaxf(a, b), fmaxf(c, d)));
        }
#pragma unroll
        for (int off = 32; off > 0; off >>= 1) mx = fmaxf(mx, __shfl_xor(mx, off));
        if (lane == 0) red[wv] = mx;
        __syncthreads();
        mx = fmaxf(fmaxf(red[0], red[1]), fmaxf(red[2], red[3]));
        float sum = 0.f;
#pragma unroll
        for (int k = 0; k < 32; k++) { v[k] = expf(v[k] - mx); sum += v[k]; }
#pragma unroll
        for (int off = 32; off > 0; off >>= 1) sum += __shfl_xor(sum, off);
        if (lane == 0) red[4 + wv] = sum;
        __syncthreads();
        float inv = 1.f / (red[4] + red[5] + red[6] + red[7]);
#pragma unroll
        for (int s = 0; s < 8; s++) {
            ushort4 o;
            o.x = f2b(v[s * 4 + 0] * inv); o.y = f2b(v[s * 4 + 1] * inv);
            o.z = f2b(v[s * 4 + 2] * inv); o.w = f2b(v[s * 4 + 3] * inv);
            *(ushort4*)(row + (s * 256 + tid) * 4) = o;
        }
    } else {
        typedef u16 row68[68];
        row68* t = (row68*)sh;
        const int b = bid - 2048;
        const int c0 = (b & 15) * 64, r0 = (b >> 4) * 64;   // C=1024, R=8192
        const int tx = tid & 15, ty = tid >> 4;
#pragma unroll
        for (int i = 0; i < 4; i++) {
            int r = r0 + ty + i * 16;
            float4 v = *(const float4*)(mem + (size_t)r * 1024 + c0 + tx * 4);
            t[tx * 4 + 0][ty + i * 16] = f2b(v.x); t[tx * 4 + 1][ty + i * 16] = f2b(v.y);
            t[tx * 4 + 2][ty + i * 16] = f2b(v.z); t[tx * 4 + 3][ty + i * 16] = f2b(v.w);
        }
        __syncthreads();
#pragma unroll
        for (int i = 0; i < 4; i++) {
            int c = ty + i * 16;
            ushort4 v;
            v.x = t[c][tx * 4 + 0]; v.y = t[c][tx * 4 + 1];
            v.z = t[c][tx * 4 + 2]; v.w = t[c][tx * 4 + 3];
            *(ushort4*)(memT + (size_t)(c0 + c) * 8192 + r0 + tx * 4) = v;
        }
    }
}

// ---------------------------------------------------------------------------
// GEMM-C (2-phase 128^2 split-K, S=2): P[z][n,md] partial = attn @ mem chunk.
// ---------------------------------------------------------------------------
template<int BM, int BN, int S, int NCOL>
__global__ __launch_bounds__(256, 4)
void k_gemm_partial(const u16* __restrict__ A, const u16* __restrict__ B,
                    int Kchunk, int ld, float* __restrict__ P)
{
    constexpr int MT = BM / 32, NT = BN / 32;
    __shared__ __align__(16) u16 smem[2 * (BM + BN) * 32 * S];

    const int nx = gridDim.x, ny = gridDim.y;
    const int f  = blockIdx.x + nx * blockIdx.y;
    const int ch = (nx * ny) >> 3;                 // chunk per XCD
    const int sw = (f & 7) * ch + (f >> 3);        // bijective (nwg%8==0)
    const int bx = sw % nx, by = sw / nx;
    const int row0 = by * BM, col0 = bx * BN;

    const u16* Ac = A + (size_t)blockIdx.z * Kchunk;
    const u16* Bc = B + (size_t)blockIdx.z * Kchunk;

    f32x4 acc[MT][NT];
    gemm_core_db<BM, BN, S>(Ac, Bc, Kchunk, ld, row0, col0, smem, acc);

    float* Pz = P + (size_t)blockIdx.z * 2048 * NCOL;
    const int tid = threadIdx.x, lane = tid & 63, wv = tid >> 6;
    const int wr = wv >> 1, wc = wv & 1, lr = lane & 15, kg = lane >> 4;
#pragma unroll
    for (int i = 0; i < MT; i++)
#pragma unroll
        for (int r = 0; r < 4; r++) {
            int n = row0 + wr * (BM / 2) + i * 16 + kg * 4 + r;
            size_t ob = (size_t)n * NCOL;
#pragma unroll
            for (int j = 0; j < NT; j++)
                Pz[ob + col0 + wc * (BN / 2) + j * 16 + lr] = acc[i][j][r];
        }
}

// ---------------------------------------------------------------------------
// reduce 4 split-K partials into final f32 output (GEMM-C tail)
// ---------------------------------------------------------------------------
__global__ __launch_bounds__(256)
void k_reduce_out(const float* __restrict__ P, float* __restrict__ out)
{
    constexpr size_t SL = (size_t)2048 * 1024;
    size_t i = ((size_t)blockIdx.x * 256 + threadIdx.x) * 4;
    float4 a = *(const float4*)(P + i);
    float4 b = *(const float4*)(P + SL + i);
    float4 c = *(const float4*)(P + 2 * SL + i);
    float4 d = *(const float4*)(P + 3 * SL + i);
    float4 o;
    o.x = a.x + b.x + c.x + d.x;
    o.y = a.y + b.y + c.y + d.y;
    o.z = a.z + b.z + c.z + d.z;
    o.w = a.w + b.w + c.w + d.w;
    *(float4*)(out + i) = o;
}

// sentinel: distinctive output if workspace is too small (absmax ~12345)
__global__ void k_fill(float* out, int n)
{
    int i = blockIdx.x * 256 + threadIdx.x;
    if (i < n) out[i] = 12345.f;
}

// ---------------------------------------------------------------------------
extern "C" void kernel_launch(void* const* d_in, const int* in_sizes, int n_in,
                              void* d_out, int out_size, void* d_ws, size_t ws_size,
                              hipStream_t stream)
{
    const float* x     = (const float*)d_in[0];
    const float* w     = (const float*)d_in[1];
    const float* delay = (const float*)d_in[2];
    const float* bb    = (const float*)d_in[3];
    const float* gW    = (const float*)d_in[4];
    const float* gb    = (const float*)d_in[5];
    const float* na    = (const float*)d_in[6];
    const float* cW1   = (const float*)d_in[7];
    const float* cb1   = (const float*)d_in[8];
    const float* cW2   = (const float*)d_in[9];
    const float* cb2   = (const float*)d_in[10];
    const float* mask  = (const float*)d_in[11];
    const float* actw  = (const float*)d_in[12];
    const float* rW    = (const float*)d_in[13];
    const float* rb    = (const float*)d_in[14];
    const float* mem   = (const float*)d_in[15];
    (void)in_sizes; (void)n_in;

    char* ws = (char*)d_ws;
    size_t off = 0;
    auto alloc = [&](size_t bytes) {
        size_t o = off; off += (bytes + 255) & ~(size_t)255; return o;
    };
    size_t o_wts   = alloc(9 * 4);
    size_t o_gate  = alloc(2048 * 4 * 4);
    size_t o_conn  = alloc(2048 * 4);
    size_t o_y     = alloc((size_t)2048 * 4096 * 2);   // y; later aliased as memT
    size_t o_wmT   = alloc((size_t)2048 * 4096 * 2);
    size_t o_blend = alloc((size_t)2048 * 2048 * 2);
    size_t o_rwT   = alloc((size_t)8192 * 2048 * 2);   // rwT; also split-K partials
    size_t o_log   = alloc((size_t)2048 * 8192 * 2);   // logits; A-partials overflow

    if (off > ws_size) {   // loud, distinguishable failure mode
        k_fill<<<(out_size + 255) / 256, 256, 0, stream>>>((float*)d_out, out_size);
        return;
    }

    float* wts   = (float*)(ws + o_wts);
    float* gate  = (float*)(ws + o_gate);
    float* conn  = (float*)(ws + o_conn);
    u16* y       = (u16*)(ws + o_y);
    u16* wmT     = (u16*)(ws + o_wmT);
    u16* blend   = (u16*)(ws + o_blend);
    u16* rwT     = (u16*)(ws + o_rwT);
    u16* logits  = (u16*)(ws + o_log);
    u16* memT    = y;   // y dead after GEMM-A; same size (16 MB)

    // split-K partial buffers, aliased into lifetime holes:
    //   A-partials: 4 x 2048 x 2048 f32 = 64 MB @ [o_rwT, o_rwT+64MB)
    //     (rwT written AFTER reduce_blend; logits written AFTER that).
    //   C-partials: 4 x 2048 x 1024 f32 = 32 MB @ o_rwT (rwT dead after logits).
    float* pA = (float*)(ws + o_rwT);
    float* pC = (float*)(ws + o_rwT);

    // prep: small MLP ∥ gate+y ∥ wmT  (1 + 512 + 1024 blocks)
    k_prep<<<1537, 256, 0, stream>>>(na, cW1, cb1, cW2, cb2, actw, conn, wts,
                                     x, gW, gb, gate, y, w, delay, wmT);

    // GEMM-A: partials = y[2048,4096] @ wmT[2048,4096]^T, split-K=4 (K=1024 each)
    k_gemm_a8<<<dim3(8, 8, 4), 512, 0, stream>>>(y, wmT, pA);
    k_reduce_blend<<<2048, 256, 0, stream>>>(pA, gate, conn, mask, wts, bb, blend);

    k_transpose<<<dim3(128, 32), 256, 0, stream>>>(rW, rwT, 2048, 8192);
    k_gemm_logits8<<<dim3(32, 8), 512, 0, stream>>>(blend, rwT, rb, logits);

    // softmax(logits) ∥ transpose(mem -> memT)
    k_post<<<4096, 256, 0, stream>>>(logits, mem, memT);

    // GEMM-C: out-partials = attn[2048,8192] @ memT[1024,8192]^T, split-K=4 (K=2048)
    k_gemm_partial<128, 128, 2, 1024><<<dim3(8, 16, 4), 256, 0, stream>>>(
        logits, memT, 2048, 8192, pC);
    k_reduce_out<<<2048, 256, 0, stream>>>(pC, (float*)d_out);
}

// Round 7
// 428.102 us; speedup vs baseline: 1.0653x; 1.0653x over previous
//
#include <hip/hip_runtime.h>

// ============================================================================
// PlasticityModelMoE — MI355X (gfx950). Inputs f32, output f32, bf16 MFMA.
// R14: REVERT the R13 phase-merge (it regressed: MfmaUtil 40->30%, logits8
// 67->94us — the per-phase barrier pairs are load-bearing in this 1-block/CU
// lockstep schedule). gemm256_core8 restored to the proven R12 7-barrier
// 4-phase form (af03/af47 register reuse, spread staging A@ph0/B@ph1,
// pure-register ph3, 3-bit swizzle, 0 bank conflicts).
// KEPT from R13: k_prep fusion (small ∥ gate_y ∥ wmT), k_post fusion
// (softmax ∥ transpose(mem)), GEMM-C S=2.
// ============================================================================

typedef unsigned short u16;
typedef __attribute__((ext_vector_type(8))) short bf16x8;   // 8 bf16 = 4 VGPRs
typedef __attribute__((ext_vector_type(4))) float f32x4;

__device__ __forceinline__ float b2f(u16 h) {
    union { unsigned u; float f; } v; v.u = ((unsigned)h) << 16; return v.f;
}
__device__ __forceinline__ u16 f2b(float f) {
    union { float f; unsigned u; } v; v.f = f;
    unsigned u = v.u;
    return (u16)((u + 0x7fffu + ((u >> 16) & 1u)) >> 16);   // round-nearest-even
}

// async global->LDS, 16B per lane (wave-uniform base + lane*16 — m97 pattern).
__device__ __forceinline__ void async_copy16(void* lds, const void* g) {
    __builtin_amdgcn_global_load_lds(
        (__attribute__((address_space(1))) void*)(g),
        (__attribute__((address_space(3))) void*)(lds), 16, 0, 0);
}

// 3-bit swizzle for 128B-row tiles: 16B-slot bits [6:4] ^= row bits [9:7].
// Involution; conflict-free ds_read_b128 (R11: BANK_CONFLICT -> 0).
__device__ __forceinline__ int swz(int o) { return o ^ (((o >> 7) & 7) << 4); }

// 2-bit swizzle for 64B-row tiles (2-phase core): slot ^= row&3. 8way->4way.
__device__ __forceinline__ int swz64(int kg, int row) { return kg ^ (row & 3); }

// ---------------------------------------------------------------------------
// 256x256 4-phase/7-barrier GEMM core (R12-proven). C = A[256,K]*B[256,K]^T.
// 512 thr / 8 waves as 2(M) x 4(N); per-wave 128x64; acc[8][4] f32x4.
// lds: 128 KiB = 2 bufs x { A: 2x(128x64) halves, B: same } bf16, swizzled.
// Ktiles = K/64 (>=2). ld = row stride of A and B in elements.
// ---------------------------------------------------------------------------
__device__ __forceinline__ void stage_tile256(const u16* __restrict__ src, int ld,
                                              int base0, int k0,
                                              char* ldsbase, int tid)
{
#pragma unroll
    for (int h = 0; h < 2; h++)
#pragma unroll
        for (int it = 0; it < 2; it++) {
            int o = it * 8192 + tid * 16;          // linear LDS byte offset
            int s = swz(o);                        // logical source offset
            int r = s >> 7;                        // row within 128-row half
            int c = (s & 127) >> 1;                // bf16 col (multiple of 8)
            async_copy16(ldsbase + h * 16384 + o,
                         src + (size_t)(base0 + h * 128 + r) * ld + k0 + c);
        }
}

__device__ __forceinline__ void gemm256_core8(const u16* __restrict__ A,
                                              const u16* __restrict__ B,
                                              int Ktiles, int ld,
                                              int row0, int col0,
                                              char* lds, f32x4 (&acc)[8][4])
{
    const int tid  = threadIdx.x;
    const int lane = tid & 63;
    const int wv   = tid >> 6;
    const int wr   = wv >> 2;          // 0..1  (M half)
    const int wc   = wv & 3;           // 0..3  (N quarter)
    const int lr   = lane & 15, kg = lane >> 4;

#pragma unroll
    for (int i = 0; i < 8; i++)
#pragma unroll
        for (int j = 0; j < 4; j++) {
            f32x4 z = {0.f, 0.f, 0.f, 0.f};
            acc[i][j] = z;
        }

    // prologue: stage tile 0 into buf 0
    stage_tile256(A, ld, row0, 0, lds, tid);
    stage_tile256(B, ld, col0, 0, lds + 32768, tid);
    asm volatile("s_waitcnt vmcnt(0)" ::: "memory");
    __builtin_amdgcn_s_barrier();

    bf16x8 af03[4][2], af47[4][2], bfr[2][2];

    for (int t = 0; t < Ktiles; t++) {
        const int buf = (t & 1) << 16;
        const char* sA = lds + buf + wr * 16384;
        const char* sB = lds + buf + 32768 + ((wc >> 1) * 16384);
        char* nb = lds + (((t + 1) & 1) << 16);
        const bool pf = (t + 1 < Ktiles);

        auto rdA = [&](int i, int ks) {
            int off = (i * 16 + lr) * 128 + ks * 64 + kg * 16;
            return *(const bf16x8*)(sA + swz(off));
        };
        auto rdB = [&](int j, int ks) {
            int off = ((wc & 1) * 64 + j * 16 + lr) * 128 + ks * 64 + kg * 16;
            return *(const bf16x8*)(sB + swz(off));
        };

        // ---- phase 0: read A m0-3 + B n0-1; stage A(t+1); MFMA m0-3 x n0-1
#pragma unroll
        for (int i = 0; i < 4; i++) { af03[i][0] = rdA(i, 0); af03[i][1] = rdA(i, 1); }
#pragma unroll
        for (int j = 0; j < 2; j++) { bfr[j][0] = rdB(j, 0); bfr[j][1] = rdB(j, 1); }
        if (pf) stage_tile256(A, ld, row0, (t + 1) * 64, nb, tid);
        __builtin_amdgcn_s_barrier();
        __builtin_amdgcn_s_setprio(1);
#pragma unroll
        for (int i = 0; i < 4; i++)
#pragma unroll
            for (int j = 0; j < 2; j++) {
                acc[i][j] = __builtin_amdgcn_mfma_f32_16x16x32_bf16(af03[i][0], bfr[j][0], acc[i][j], 0, 0, 0);
                acc[i][j] = __builtin_amdgcn_mfma_f32_16x16x32_bf16(af03[i][1], bfr[j][1], acc[i][j], 0, 0, 0);
            }
        __builtin_amdgcn_s_setprio(0);
        __builtin_amdgcn_s_barrier();

        // ---- phase 1: read A m4-7; stage B(t+1); MFMA m4-7 x n0-1 ----
#pragma unroll
        for (int i = 0; i < 4; i++) { af47[i][0] = rdA(4 + i, 0); af47[i][1] = rdA(4 + i, 1); }
        if (pf) stage_tile256(B, ld, col0, (t + 1) * 64, nb + 32768, tid);
        __builtin_amdgcn_s_barrier();
        __builtin_amdgcn_s_setprio(1);
#pragma unroll
        for (int i = 0; i < 4; i++)
#pragma unroll
            for (int j = 0; j < 2; j++) {
                acc[4 + i][j] = __builtin_amdgcn_mfma_f32_16x16x32_bf16(af47[i][0], bfr[j][0], acc[4 + i][j], 0, 0, 0);
                acc[4 + i][j] = __builtin_amdgcn_mfma_f32_16x16x32_bf16(af47[i][1], bfr[j][1], acc[4 + i][j], 0, 0, 0);
            }
        __builtin_amdgcn_s_setprio(0);
        __builtin_amdgcn_s_barrier();

        // ---- phase 2: read B n2-3; MFMA m4-7 x n2-3 ----
#pragma unroll
        for (int j = 0; j < 2; j++) { bfr[j][0] = rdB(2 + j, 0); bfr[j][1] = rdB(2 + j, 1); }
        __builtin_amdgcn_s_barrier();
        __builtin_amdgcn_s_setprio(1);
#pragma unroll
        for (int i = 0; i < 4; i++)
#pragma unroll
            for (int j = 0; j < 2; j++) {
                acc[4 + i][2 + j] = __builtin_amdgcn_mfma_f32_16x16x32_bf16(af47[i][0], bfr[j][0], acc[4 + i][2 + j], 0, 0, 0);
                acc[4 + i][2 + j] = __builtin_amdgcn_mfma_f32_16x16x32_bf16(af47[i][1], bfr[j][1], acc[4 + i][2 + j], 0, 0, 0);
            }
        __builtin_amdgcn_s_setprio(0);
        __builtin_amdgcn_s_barrier();

        // ---- phase 3: pure-register MFMA m0-3 x n2-3 (af03 still live);
        //      tile-boundary vmcnt (loads are >=2 phases old) + barrier ----
        __builtin_amdgcn_s_setprio(1);
#pragma unroll
        for (int i = 0; i < 4; i++)
#pragma unroll
            for (int j = 0; j < 2; j++) {
                acc[i][2 + j] = __builtin_amdgcn_mfma_f32_16x16x32_bf16(af03[i][0], bfr[j][0], acc[i][2 + j], 0, 0, 0);
                acc[i][2 + j] = __builtin_amdgcn_mfma_f32_16x16x32_bf16(af03[i][1], bfr[j][1], acc[i][2 + j], 0, 0, 0);
            }
        __builtin_amdgcn_s_setprio(0);
        asm volatile("s_waitcnt vmcnt(0)" ::: "memory");
        __builtin_amdgcn_s_barrier();
    }
}

// ---------------------------------------------------------------------------
// Double-buffered 2-phase GEMM core — used by GEMM-C. S windows of BK=32;
// 64B-row LDS; 2-bit slot swizzle (slot ^= row&3) on both sides.
// ---------------------------------------------------------------------------
template<int BM, int BN, int S>
__device__ __forceinline__ void gemm_core_db(const u16* __restrict__ A,
                                             const u16* __restrict__ B,
                                             int Kloop, int ld,
                                             int row0, int col0,
                                             u16* smem,
                                             f32x4 (&acc)[BM / 32][BN / 32])
{
    constexpr int MT = BM / 32, NT = BN / 32;
    constexpr int STG = (BM + BN) * 32;     // u16 per stage
    constexpr int SET = STG * S;            // u16 per buffer set
    const int tid  = threadIdx.x;
    const int lane = tid & 63;
    const int wv   = tid >> 6;
    const int wr   = wv >> 1, wc = wv & 1;
    const int lr   = lane & 15, kg = lane >> 4;

#pragma unroll
    for (int i = 0; i < MT; i++)
#pragma unroll
        for (int j = 0; j < NT; j++) {
            f32x4 z = {0.f, 0.f, 0.f, 0.f};
            acc[i][j] = z;
        }

    auto stage_in = [&](u16* set, int k0) {
#pragma unroll
        for (int c = tid; c < BM * 4; c += 256) {
            int row = c >> 2, sl = swz64(c & 3, row);
            const u16* gA = A + (size_t)(row0 + row) * ld + k0 + sl * 8;
#pragma unroll
            for (int s = 0; s < S; s++)
                async_copy16(set + s * STG + c * 8, gA + s * 32);
        }
#pragma unroll
        for (int c = tid; c < BN * 4; c += 256) {
            int row = c >> 2, sl = swz64(c & 3, row);
            const u16* gB = B + (size_t)(col0 + row) * ld + k0 + sl * 8;
#pragma unroll
            for (int s = 0; s < S; s++)
                async_copy16(set + s * STG + BM * 32 + c * 8, gB + s * 32);
        }
    };

    stage_in(smem, 0);
    __syncthreads();           // drain prologue staging

    int p = 0;
    for (int k0 = 0; k0 < Kloop; k0 += 32 * S) {
        if (k0 + 32 * S < Kloop)
            stage_in(smem + (p ^ 1) * SET, k0 + 32 * S);   // prefetch next window
        u16* set = smem + p * SET;
#pragma unroll
        for (int s = 0; s < S; s++) {
            const u16* sA = set + s * STG;
            const u16* sB = sA + BM * 32;
            bf16x8 af[MT], bfr[NT];
#pragma unroll
            for (int i = 0; i < MT; i++) {
                int row = wr * (BM / 2) + i * 16 + lr;
                af[i] = *(const bf16x8*)(sA + (row * 32 + swz64(kg, row) * 8));
            }
#pragma unroll
            for (int j = 0; j < NT; j++) {
                int row = wc * (BN / 2) + j * 16 + lr;
                bfr[j] = *(const bf16x8*)(sB + (row * 32 + swz64(kg, row) * 8));
            }
#pragma unroll
            for (int i = 0; i < MT; i++)
#pragma unroll
                for (int j = 0; j < NT; j++)
                    acc[i][j] = __builtin_amdgcn_mfma_f32_16x16x32_bf16(
                                    af[i], bfr[j], acc[i][j], 0, 0, 0);
        }
        __syncthreads();       // one barrier/window; vmcnt drain overlapped above
        p ^= 1;
    }
}

// ---------------------------------------------------------------------------
// k_prep: fused independent pre-GEMM work, block-role partitioned.
//   block 0       : conn = sigmoid(relu(na@W1+b1)@W2+b2); wts = softmax(act_w)
//   blocks 1-512  : gate softmax + y = x*gate (bf16)
//   blocks 513-1536: wmT[u, d*4+b] = w[d,u,b]*sigmoid(delay[d,u,b]) (bf16)
// ---------------------------------------------------------------------------
__global__ __launch_bounds__(256)
void k_prep(const float* __restrict__ na, const float* __restrict__ W1,
            const float* __restrict__ b1, const float* __restrict__ W2,
            const float* __restrict__ b2, const float* __restrict__ actw,
            float* __restrict__ conn, float* __restrict__ wts,
            const float* __restrict__ x, const float* __restrict__ gW,
            const float* __restrict__ gb, float* __restrict__ gate,
            u16* __restrict__ y,
            const float* __restrict__ w, const float* __restrict__ delay,
            u16* __restrict__ wmT)
{
    __shared__ __align__(16) char sh[256 * 32 * 4 + 128];
    const int bid = blockIdx.x;
    const int tid = threadIdx.x;

    if (bid == 0) {
        // ---- role: small MLP + act-weight softmax ----
        float* red = (float*)sh;
        float* hsh = (float*)(sh + 256 * 32 * 4);
        float h[32];
#pragma unroll
        for (int k = 0; k < 32; k++) h[k] = 0.f;
        for (int u = tid; u < 2048; u += 256) {
            float nav = na[u];
            const float* row = W1 + u * 32;
#pragma unroll
            for (int k = 0; k < 32; k++) h[k] += nav * row[k];
        }
#pragma unroll
        for (int k = 0; k < 32; k++) red[tid * 32 + k] = h[k];
        for (int s = 128; s > 0; s >>= 1) {
            __syncthreads();
            if (tid < s)
#pragma unroll
                for (int k = 0; k < 32; k++) red[tid * 32 + k] += red[(tid + s) * 32 + k];
        }
        __syncthreads();
        if (tid < 32) hsh[tid] = fmaxf(red[tid] + b1[tid], 0.f);
        if (tid == 0) {
            float e[9], m = -1e30f;
            for (int i = 0; i < 9; i++) { e[i] = actw[i]; m = fmaxf(m, e[i]); }
            float s = 0.f;
            for (int i = 0; i < 9; i++) { e[i] = expf(e[i] - m); s += e[i]; }
            for (int i = 0; i < 9; i++) wts[i] = e[i] / s;
        }
        __syncthreads();
        for (int u = tid; u < 2048; u += 256) {
            float a = 0.f;
#pragma unroll
            for (int k = 0; k < 32; k++) a += hsh[k] * W2[k * 2048 + u];
            conn[u] = 1.f / (1.f + expf(-(a + b2[u])));
        }
    } else if (bid <= 512) {
        // ---- role: gate softmax + y = x*gate ----
        const int lane = tid & 63, wvx = tid >> 6;
        const int n = (bid - 1) * 4 + wvx;
        const float* xr = x + (size_t)n * 1024;
        float a0 = 0, a1 = 0, a2 = 0, a3 = 0;
        float xv[16];
#pragma unroll
        for (int s = 0; s < 16; s++) {
            int d = s * 64 + lane;
            float xd = xr[d]; xv[s] = xd;
            float4 g4 = *(const float4*)(gW + d * 4);
            a0 += xd * g4.x; a1 += xd * g4.y; a2 += xd * g4.z; a3 += xd * g4.w;
        }
#pragma unroll
        for (int off = 32; off > 0; off >>= 1) {
            a0 += __shfl_xor(a0, off); a1 += __shfl_xor(a1, off);
            a2 += __shfl_xor(a2, off); a3 += __shfl_xor(a3, off);
        }
        a0 += gb[0]; a1 += gb[1]; a2 += gb[2]; a3 += gb[3];
        float m = fmaxf(fmaxf(a0, a1), fmaxf(a2, a3));
        float e0 = expf(a0 - m), e1 = expf(a1 - m), e2 = expf(a2 - m), e3 = expf(a3 - m);
        float inv = 1.f / (e0 + e1 + e2 + e3);
        float g0 = e0 * inv, g1 = e1 * inv, g2 = e2 * inv, g3 = e3 * inv;
        if (lane == 0) *(float4*)(gate + n * 4) = make_float4(g0, g1, g2, g3);
#pragma unroll
        for (int s = 0; s < 16; s++) {
            int d = s * 64 + lane;
            ushort4 o;
            o.x = f2b(xv[s] * g0); o.y = f2b(xv[s] * g1);
            o.z = f2b(xv[s] * g2); o.w = f2b(xv[s] * g3);
            *(ushort4*)(y + (size_t)n * 4096 + d * 4) = o;
        }
    } else {
        // ---- role: wmT transpose+cast ----
        typedef ushort4 row65[65];
        row65* tile = (row65*)sh;
        const int b = bid - 513;
        const int u0 = (b & 31) * 64, d0 = (b >> 5) * 32;
        const int tx = tid & 63, ty = tid >> 6;
#pragma unroll
        for (int i = 0; i < 8; i++) {
            int d = i * 4 + ty;
            size_t idx = ((size_t)(d0 + d) * 2048 + (u0 + tx)) * 4;
            float4 w4 = *(const float4*)(w + idx);
            float4 d4 = *(const float4*)(delay + idx);
            ushort4 o;
            o.x = f2b(w4.x / (1.f + expf(-d4.x)));
            o.y = f2b(w4.y / (1.f + expf(-d4.y)));
            o.z = f2b(w4.z / (1.f + expf(-d4.z)));
            o.w = f2b(w4.w / (1.f + expf(-d4.w)));
            tile[d][tx] = o;
        }
        __syncthreads();
        const int dx = tid & 31, uy = tid >> 5;
#pragma unroll
        for (int i = 0; i < 8; i++) {
            int u = i * 8 + uy;
            *(ushort4*)(wmT + (size_t)(u0 + u) * 4096 + (d0 + dx) * 4) = tile[dx][u];
        }
    }
}

// ---------------------------------------------------------------------------
// transpose + cast: in[R,C] f32 -> out[C,R] bf16, 64x64 tiles (rW only)
// ---------------------------------------------------------------------------
__global__ __launch_bounds__(256)
void k_transpose(const float* __restrict__ in, u16* __restrict__ out, int R, int C)
{
    __shared__ __align__(16) u16 t[64][68];
    const int tid = threadIdx.x, tx = tid & 15, ty = tid >> 4;
    const int c0 = blockIdx.x * 64, r0 = blockIdx.y * 64;
#pragma unroll
    for (int i = 0; i < 4; i++) {
        int r = r0 + ty + i * 16;
        float4 v = *(const float4*)(in + (size_t)r * C + c0 + tx * 4);
        t[tx * 4 + 0][ty + i * 16] = f2b(v.x); t[tx * 4 + 1][ty + i * 16] = f2b(v.y);
        t[tx * 4 + 2][ty + i * 16] = f2b(v.z); t[tx * 4 + 3][ty + i * 16] = f2b(v.w);
    }
    __syncthreads();
#pragma unroll
    for (int i = 0; i < 4; i++) {
        int c = ty + i * 16;
        ushort4 v;
        v.x = t[c][tx * 4 + 0]; v.y = t[c][tx * 4 + 1];
        v.z = t[c][tx * 4 + 2]; v.w = t[c][tx * 4 + 3];
        *(ushort4*)(out + (size_t)(c0 + c) * R + r0 + tx * 4) = v;
    }
}

// ---------------------------------------------------------------------------
// 8-way activation blend
// ---------------------------------------------------------------------------
__device__ __forceinline__ float act_blend(float a,
    float w0, float w1, float w2, float w3,
    float w4, float w5, float w6, float w7)
{
    float sig = 1.f / (1.f + expf(-a));
    float elu = (a > 0.f) ? a : (expf(a) - 1.f);
    float th  = tanhf(a);
    float rel = fmaxf(a, 0.f);
    float sil = a * sig;
    float gel = a * 0.5f * (1.f + erff(a * 0.70710678118654752f));
    float sel = (a > 0.f) ? 1.0507009873554805f * a
                          : 1.0507009873554805f * 1.6732632423543772f * (expf(a) - 1.f);
    float sp  = (a > 20.f) ? a : log1pf(expf(a));
    float mish = a * tanhf(sp);
    return w0 * sig + w1 * elu + w2 * th + w3 * rel + w4 * sil + w5 * gel
         + w6 * sel + w7 * mish;
}

// ---------------------------------------------------------------------------
// GEMM-A (4-phase 256^2, split-K): P[z][n,u] partial = y@wmT^T over K-chunk z.
// grid (8, 8, 4), 512 thr, LDS 128 KiB -> 256 blocks, 1/CU.
// ---------------------------------------------------------------------------
__global__ __launch_bounds__(512, 2)
void k_gemm_a8(const u16* __restrict__ A, const u16* __restrict__ B,
               float* __restrict__ P)
{
    __shared__ __align__(16) char lds[131072];
    const int row0 = blockIdx.y * 256, col0 = blockIdx.x * 256;
    const u16* Ac = A + (size_t)blockIdx.z * 1024;
    const u16* Bc = B + (size_t)blockIdx.z * 1024;

    f32x4 acc[8][4];
    gemm256_core8(Ac, Bc, 16, 4096, row0, col0, lds, acc);

    float* Pz = P + (size_t)blockIdx.z * 2048 * 2048;
    const int tid = threadIdx.x, lane = tid & 63, wv = tid >> 6;
    const int wr = wv >> 2, wc = wv & 3, lr = lane & 15, kg = lane >> 4;
#pragma unroll
    for (int i = 0; i < 8; i++)
#pragma unroll
        for (int r = 0; r < 4; r++) {
            int n = row0 + wr * 128 + i * 16 + kg * 4 + r;
            size_t ob = (size_t)n * 2048;
#pragma unroll
            for (int j = 0; j < 4; j++)
                Pz[ob + col0 + wc * 64 + j * 16 + lr] = acc[i][j][r];
        }
}

// ---------------------------------------------------------------------------
// reduce 4 split-K partials + GEMM-A epilogue:
// blend[n,u] = blend8(relu((sum_s P[s][n,u] + gate[n]·b[u])*conn[u]*mask[u]))
// ---------------------------------------------------------------------------
__global__ __launch_bounds__(256)
void k_reduce_blend(const float* __restrict__ P, const float* __restrict__ gate,
                    const float* __restrict__ conn, const float* __restrict__ mask,
                    const float* __restrict__ wts, const float* __restrict__ bbias,
                    u16* __restrict__ blend)
{
    constexpr size_t SL = (size_t)2048 * 2048;
    const int n  = blockIdx.x;
    const int u0 = threadIdx.x * 8;
    const float* base = P + (size_t)n * 2048 + u0;

    float v[8];
#pragma unroll
    for (int h = 0; h < 2; h++) {
        float4 a = *(const float4*)(base + h * 4);
        float4 b = *(const float4*)(base + SL + h * 4);
        float4 c = *(const float4*)(base + 2 * SL + h * 4);
        float4 d = *(const float4*)(base + 3 * SL + h * 4);
        v[h * 4 + 0] = a.x + b.x + c.x + d.x;
        v[h * 4 + 1] = a.y + b.y + c.y + d.y;
        v[h * 4 + 2] = a.z + b.z + c.z + d.z;
        v[h * 4 + 3] = a.w + b.w + c.w + d.w;
    }
    float4 g = *(const float4*)(gate + n * 4);
    const float w0 = wts[0], w1 = wts[1], w2 = wts[2], w3 = wts[3];
    const float w4 = wts[4], w5 = wts[5], w6 = wts[6], w7 = wts[7];

    ushort4 o[2];
#pragma unroll
    for (int j = 0; j < 8; j++) {
        int u = u0 + j;
        float4 b4 = *(const float4*)(bbias + u * 4);
        float z = v[j] + g.x * b4.x + g.y * b4.y + g.z * b4.z + g.w * b4.w;
        float a = fmaxf(z * conn[u] * mask[u], 0.f);
        u16 r = f2b(act_blend(a, w0, w1, w2, w3, w4, w5, w6, w7));
        ((u16*)o)[j] = r;
    }
    *(ushort4*)(blend + (size_t)n * 2048 + u0)     = o[0];
    *(ushort4*)(blend + (size_t)n * 2048 + u0 + 4) = o[1];
}

// ---------------------------------------------------------------------------
// GEMM-B (4-phase 256^2): logits[n,m] = blend@read_W^T + read_b (bf16 out)
// grid (32, 8), 512 thr -> 256 blocks, 1/CU.
// ---------------------------------------------------------------------------
__global__ __launch_bounds__(512, 2)
void k_gemm_logits8(const u16* __restrict__ BL, const u16* __restrict__ RWT,
                    const float* __restrict__ rbias, u16* __restrict__ out)
{
    __shared__ __align__(16) char lds[131072];
    const int row0 = blockIdx.y * 256, col0 = blockIdx.x * 256;

    f32x4 acc[8][4];
    gemm256_core8(BL, RWT, 32, 2048, row0, col0, lds, acc);

    const int tid = threadIdx.x, lane = tid & 63, wv = tid >> 6;
    const int wr = wv >> 2, wc = wv & 3, lr = lane & 15, kg = lane >> 4;
    float rb[4]; int mm[4];
#pragma unroll
    for (int j = 0; j < 4; j++) {
        mm[j] = col0 + wc * 64 + j * 16 + lr;
        rb[j] = rbias[mm[j]];
    }
#pragma unroll
    for (int i = 0; i < 8; i++)
#pragma unroll
        for (int r = 0; r < 4; r++) {
            int n = row0 + wr * 128 + i * 16 + kg * 4 + r;
            size_t ob = (size_t)n * 8192;
#pragma unroll
            for (int j = 0; j < 4; j++)
                out[ob + mm[j]] = f2b(acc[i][j][r] + rb[j]);
        }
}

// ---------------------------------------------------------------------------
// k_post: fused softmax(logits) ∥ transpose(mem -> memT).
//   blocks 0-2047   : in-place row softmax over 8192 bf16
//   blocks 2048-4095: mem[8192,1024] f32 -> memT[1024,8192] bf16
// ---------------------------------------------------------------------------
__global__ __launch_bounds__(256)
void k_post(u16* __restrict__ buf, const float* __restrict__ mem,
            u16* __restrict__ memT)
{
    __shared__ __align__(16) char sh[64 * 68 * 2 + 64];
    const int bid = blockIdx.x;
    const int tid = threadIdx.x;

    if (bid < 2048) {
        float* red = (float*)sh;
        const int lane = tid & 63, wv = tid >> 6;
        u16* row = buf + (size_t)bid * 8192;
        float v[32];
        float mx = -1e30f;
#pragma unroll
        for (int s = 0; s < 8; s++) {
            ushort4 u4 = *(const ushort4*)(row + (s * 256 + tid) * 4);
            float a = b2f(u4.x), b = b2f(u4.y), c = b2f(u4.z), d = b2f(u4.w);
            v[s * 4 + 0] = a; v[s * 4 + 1] = b; v[s * 4 + 2] = c; v[s * 4 + 3] = d;
            mx = fmaxf(mx, fmaxf(fmaxf(a, b), fmaxf(c, d)));
        }
#pragma unroll
        for (int off = 32; off > 0; off >>= 1) mx = fmaxf(mx, __shfl_xor(mx, off));
        if (lane == 0) red[wv] = mx;
        __syncthreads();
        mx = fmaxf(fmaxf(red[0], red[1]), fmaxf(red[2], red[3]));
        float sum = 0.f;
#pragma unroll
        for (int k = 0; k < 32; k++) { v[k] = expf(v[k] - mx); sum += v[k]; }
#pragma unroll
        for (int off = 32; off > 0; off >>= 1) sum += __shfl_xor(sum, off);
        if (lane == 0) red[4 + wv] = sum;
        __syncthreads();
        float inv = 1.f / (red[4] + red[5] + red[6] + red[7]);
#pragma unroll
        for (int s = 0; s < 8; s++) {
            ushort4 o;
            o.x = f2b(v[s * 4 + 0] * inv); o.y = f2b(v[s * 4 + 1] * inv);
            o.z = f2b(v[s * 4 + 2] * inv); o.w = f2b(v[s * 4 + 3] * inv);
            *(ushort4*)(row + (s * 256 + tid) * 4) = o;
        }
    } else {
        typedef u16 row68[68];
        row68* t = (row68*)sh;
        const int b = bid - 2048;
        const int c0 = (b & 15) * 64, r0 = (b >> 4) * 64;   // C=1024, R=8192
        const int tx = tid & 15, ty = tid >> 4;
#pragma unroll
        for (int i = 0; i < 4; i++) {
            int r = r0 + ty + i * 16;
            float4 v = *(const float4*)(mem + (size_t)r * 1024 + c0 + tx * 4);
            t[tx * 4 + 0][ty + i * 16] = f2b(v.x); t[tx * 4 + 1][ty + i * 16] = f2b(v.y);
            t[tx * 4 + 2][ty + i * 16] = f2b(v.z); t[tx * 4 + 3][ty + i * 16] = f2b(v.w);
        }
        __syncthreads();
#pragma unroll
        for (int i = 0; i < 4; i++) {
            int c = ty + i * 16;
            ushort4 v;
            v.x = t[c][tx * 4 + 0]; v.y = t[c][tx * 4 + 1];
            v.z = t[c][tx * 4 + 2]; v.w = t[c][tx * 4 + 3];
            *(ushort4*)(memT + (size_t)(c0 + c) * 8192 + r0 + tx * 4) = v;
        }
    }
}

// ---------------------------------------------------------------------------
// GEMM-C (2-phase 128^2 split-K, S=2): P[z][n,md] partial = attn @ mem chunk.
// ---------------------------------------------------------------------------
template<int BM, int BN, int S, int NCOL>
__global__ __launch_bounds__(256, 4)
void k_gemm_partial(const u16* __restrict__ A, const u16* __restrict__ B,
                    int Kchunk, int ld, float* __restrict__ P)
{
    constexpr int MT = BM / 32, NT = BN / 32;
    __shared__ __align__(16) u16 smem[2 * (BM + BN) * 32 * S];

    const int nx = gridDim.x, ny = gridDim.y;
    const int f  = blockIdx.x + nx * blockIdx.y;
    const int ch = (nx * ny) >> 3;                 // chunk per XCD
    const int sw = (f & 7) * ch + (f >> 3);        // bijective (nwg%8==0)
    const int bx = sw % nx, by = sw / nx;
    const int row0 = by * BM, col0 = bx * BN;

    const u16* Ac = A + (size_t)blockIdx.z * Kchunk;
    const u16* Bc = B + (size_t)blockIdx.z * Kchunk;

    f32x4 acc[MT][NT];
    gemm_core_db<BM, BN, S>(Ac, Bc, Kchunk, ld, row0, col0, smem, acc);

    float* Pz = P + (size_t)blockIdx.z * 2048 * NCOL;
    const int tid = threadIdx.x, lane = tid & 63, wv = tid >> 6;
    const int wr = wv >> 1, wc = wv & 1, lr = lane & 15, kg = lane >> 4;
#pragma unroll
    for (int i = 0; i < MT; i++)
#pragma unroll
        for (int r = 0; r < 4; r++) {
            int n = row0 + wr * (BM / 2) + i * 16 + kg * 4 + r;
            size_t ob = (size_t)n * NCOL;
#pragma unroll
            for (int j = 0; j < NT; j++)
                Pz[ob + col0 + wc * (BN / 2) + j * 16 + lr] = acc[i][j][r];
        }
}

// ---------------------------------------------------------------------------
// reduce 4 split-K partials into final f32 output (GEMM-C tail)
// ---------------------------------------------------------------------------
__global__ __launch_bounds__(256)
void k_reduce_out(const float* __restrict__ P, float* __restrict__ out)
{
    constexpr size_t SL = (size_t)2048 * 1024;
    size_t i = ((size_t)blockIdx.x * 256 + threadIdx.x) * 4;
    float4 a = *(const float4*)(P + i);
    float4 b = *(const float4*)(P + SL + i);
    float4 c = *(const float4*)(P + 2 * SL + i);
    float4 d = *(const float4*)(P + 3 * SL + i);
    float4 o;
    o.x = a.x + b.x + c.x + d.x;
    o.y = a.y + b.y + c.y + d.y;
    o.z = a.z + b.z + c.z + d.z;
    o.w = a.w + b.w + c.w + d.w;
    *(float4*)(out + i) = o;
}

// sentinel: distinctive output if workspace is too small (absmax ~12345)
__global__ void k_fill(float* out, int n)
{
    int i = blockIdx.x * 256 + threadIdx.x;
    if (i < n) out[i] = 12345.f;
}

// ---------------------------------------------------------------------------
extern "C" void kernel_launch(void* const* d_in, const int* in_sizes, int n_in,
                              void* d_out, int out_size, void* d_ws, size_t ws_size,
                              hipStream_t stream)
{
    const float* x     = (const float*)d_in[0];
    const float* w     = (const float*)d_in[1];
    const float* delay = (const float*)d_in[2];
    const float* bb    = (const float*)d_in[3];
    const float* gW    = (const float*)d_in[4];
    const float* gb    = (const float*)d_in[5];
    const float* na    = (const float*)d_in[6];
    const float* cW1   = (const float*)d_in[7];
    const float* cb1   = (const float*)d_in[8];
    const float* cW2   = (const float*)d_in[9];
    const float* cb2   = (const float*)d_in[10];
    const float* mask  = (const float*)d_in[11];
    const float* actw  = (const float*)d_in[12];
    const float* rW    = (const float*)d_in[13];
    const float* rb    = (const float*)d_in[14];
    const float* mem   = (const float*)d_in[15];
    (void)in_sizes; (void)n_in;

    char* ws = (char*)d_ws;
    size_t off = 0;
    auto alloc = [&](size_t bytes) {
        size_t o = off; off += (bytes + 255) & ~(size_t)255; return o;
    };
    size_t o_wts   = alloc(9 * 4);
    size_t o_gate  = alloc(2048 * 4 * 4);
    size_t o_conn  = alloc(2048 * 4);
    size_t o_y     = alloc((size_t)2048 * 4096 * 2);   // y; later aliased as memT
    size_t o_wmT   = alloc((size_t)2048 * 4096 * 2);
    size_t o_blend = alloc((size_t)2048 * 2048 * 2);
    size_t o_rwT   = alloc((size_t)8192 * 2048 * 2);   // rwT; also split-K partials
    size_t o_log   = alloc((size_t)2048 * 8192 * 2);   // logits; A-partials overflow

    if (off > ws_size) {   // loud, distinguishable failure mode
        k_fill<<<(out_size + 255) / 256, 256, 0, stream>>>((float*)d_out, out_size);
        return;
    }

    float* wts   = (float*)(ws + o_wts);
    float* gate  = (float*)(ws + o_gate);
    float* conn  = (float*)(ws + o_conn);
    u16* y       = (u16*)(ws + o_y);
    u16* wmT     = (u16*)(ws + o_wmT);
    u16* blend   = (u16*)(ws + o_blend);
    u16* rwT     = (u16*)(ws + o_rwT);
    u16* logits  = (u16*)(ws + o_log);
    u16* memT    = y;   // y dead after GEMM-A; same size (16 MB)

    // split-K partial buffers, aliased into lifetime holes:
    //   A-partials: 4 x 2048 x 2048 f32 = 64 MB @ [o_rwT, o_rwT+64MB)
    //     (rwT written AFTER reduce_blend; logits written AFTER that).
    //   C-partials: 4 x 2048 x 1024 f32 = 32 MB @ o_rwT (rwT dead after logits).
    float* pA = (float*)(ws + o_rwT);
    float* pC = (float*)(ws + o_rwT);

    // prep: small MLP ∥ gate+y ∥ wmT  (1 + 512 + 1024 blocks)
    k_prep<<<1537, 256, 0, stream>>>(na, cW1, cb1, cW2, cb2, actw, conn, wts,
                                     x, gW, gb, gate, y, w, delay, wmT);

    // GEMM-A: partials = y[2048,4096] @ wmT[2048,4096]^T, split-K=4 (K=1024 each)
    k_gemm_a8<<<dim3(8, 8, 4), 512, 0, stream>>>(y, wmT, pA);
    k_reduce_blend<<<2048, 256, 0, stream>>>(pA, gate, conn, mask, wts, bb, blend);

    k_transpose<<<dim3(128, 32), 256, 0, stream>>>(rW, rwT, 2048, 8192);
    k_gemm_logits8<<<dim3(32, 8), 512, 0, stream>>>(blend, rwT, rb, logits);

    // softmax(logits) ∥ transpose(mem -> memT)
    k_post<<<4096, 256, 0, stream>>>(logits, mem, memT);

    // GEMM-C: out-partials = attn[2048,8192] @ memT[1024,8192]^T, split-K=4 (K=2048)
    k_gemm_partial<128, 128, 2, 1024><<<dim3(8, 16, 4), 256, 0, stream>>>(
        logits, memT, 2048, 8192, pC);
    k_reduce_out<<<2048, 256, 0, stream>>>(pC, (float*)d_out);
}

// Round 8
// 417.351 us; speedup vs baseline: 1.0927x; 1.0258x over previous
//
#include <hip/hip_runtime.h>

// ============================================================================
// PlasticityModelMoE — MI355X (gfx950). Inputs f32, output f32, bf16 MFMA.
// R15: single change vs R14 — af47 ds_reads issued in ph0 (after af03/b01).
// DS retires in order -> compiler emits counted lgkmcnt(8) before ph0 MFMA;
// af47's LDS service overlaps ph0's MFMA cluster; ph1 becomes read-free.
// Zero register growth (af47 array already exists; we're pinned at 256
// VGPR+AGPR for 2 waves/SIMD). Barriers unchanged (R13: load-bearing).
// Everything else identical to R14 (k_prep/k_post fusions, GEMM-C S=2).
// ============================================================================

typedef unsigned short u16;
typedef __attribute__((ext_vector_type(8))) short bf16x8;   // 8 bf16 = 4 VGPRs
typedef __attribute__((ext_vector_type(4))) float f32x4;

__device__ __forceinline__ float b2f(u16 h) {
    union { unsigned u; float f; } v; v.u = ((unsigned)h) << 16; return v.f;
}
__device__ __forceinline__ u16 f2b(float f) {
    union { float f; unsigned u; } v; v.f = f;
    unsigned u = v.u;
    return (u16)((u + 0x7fffu + ((u >> 16) & 1u)) >> 16);   // round-nearest-even
}

// async global->LDS, 16B per lane (wave-uniform base + lane*16 — m97 pattern).
__device__ __forceinline__ void async_copy16(void* lds, const void* g) {
    __builtin_amdgcn_global_load_lds(
        (__attribute__((address_space(1))) void*)(g),
        (__attribute__((address_space(3))) void*)(lds), 16, 0, 0);
}

// 3-bit swizzle for 128B-row tiles: 16B-slot bits [6:4] ^= row bits [9:7].
// Involution; conflict-free ds_read_b128 (R11: BANK_CONFLICT -> 0).
__device__ __forceinline__ int swz(int o) { return o ^ (((o >> 7) & 7) << 4); }

// 2-bit swizzle for 64B-row tiles (2-phase core): slot ^= row&3. 8way->4way.
__device__ __forceinline__ int swz64(int kg, int row) { return kg ^ (row & 3); }

// ---------------------------------------------------------------------------
// 256x256 4-phase/7-barrier GEMM core. C = A[256,K]*B[256,K]^T.
// 512 thr / 8 waves as 2(M) x 4(N); per-wave 128x64; acc[8][4] f32x4.
// lds: 128 KiB = 2 bufs x { A: 2x(128x64) halves, B: same } bf16, swizzled.
// Ktiles = K/64 (>=2). ld = row stride of A and B in elements.
// ---------------------------------------------------------------------------
__device__ __forceinline__ void stage_tile256(const u16* __restrict__ src, int ld,
                                              int base0, int k0,
                                              char* ldsbase, int tid)
{
#pragma unroll
    for (int h = 0; h < 2; h++)
#pragma unroll
        for (int it = 0; it < 2; it++) {
            int o = it * 8192 + tid * 16;          // linear LDS byte offset
            int s = swz(o);                        // logical source offset
            int r = s >> 7;                        // row within 128-row half
            int c = (s & 127) >> 1;                // bf16 col (multiple of 8)
            async_copy16(ldsbase + h * 16384 + o,
                         src + (size_t)(base0 + h * 128 + r) * ld + k0 + c);
        }
}

__device__ __forceinline__ void gemm256_core8(const u16* __restrict__ A,
                                              const u16* __restrict__ B,
                                              int Ktiles, int ld,
                                              int row0, int col0,
                                              char* lds, f32x4 (&acc)[8][4])
{
    const int tid  = threadIdx.x;
    const int lane = tid & 63;
    const int wv   = tid >> 6;
    const int wr   = wv >> 2;          // 0..1  (M half)
    const int wc   = wv & 3;           // 0..3  (N quarter)
    const int lr   = lane & 15, kg = lane >> 4;

#pragma unroll
    for (int i = 0; i < 8; i++)
#pragma unroll
        for (int j = 0; j < 4; j++) {
            f32x4 z = {0.f, 0.f, 0.f, 0.f};
            acc[i][j] = z;
        }

    // prologue: stage tile 0 into buf 0
    stage_tile256(A, ld, row0, 0, lds, tid);
    stage_tile256(B, ld, col0, 0, lds + 32768, tid);
    asm volatile("s_waitcnt vmcnt(0)" ::: "memory");
    __builtin_amdgcn_s_barrier();

    bf16x8 af03[4][2], af47[4][2], bfr[2][2];

    for (int t = 0; t < Ktiles; t++) {
        const int buf = (t & 1) << 16;
        const char* sA = lds + buf + wr * 16384;
        const char* sB = lds + buf + 32768 + ((wc >> 1) * 16384);
        char* nb = lds + (((t + 1) & 1) << 16);
        const bool pf = (t + 1 < Ktiles);

        auto rdA = [&](int i, int ks) {
            int off = (i * 16 + lr) * 128 + ks * 64 + kg * 16;
            return *(const bf16x8*)(sA + swz(off));
        };
        auto rdB = [&](int j, int ks) {
            int off = ((wc & 1) * 64 + j * 16 + lr) * 128 + ks * 64 + kg * 16;
            return *(const bf16x8*)(sB + swz(off));
        };

        // ---- phase 0: read af03 + b01, THEN issue af47 reads (in-order DS
        //      retire -> counted lgkm before MFMA; af47 service overlaps
        //      ph0's MFMA cluster); stage A(t+1); MFMA m0-3 x n0-1 ----
#pragma unroll
        for (int i = 0; i < 4; i++) { af03[i][0] = rdA(i, 0); af03[i][1] = rdA(i, 1); }
#pragma unroll
        for (int j = 0; j < 2; j++) { bfr[j][0] = rdB(j, 0); bfr[j][1] = rdB(j, 1); }
#pragma unroll
        for (int i = 0; i < 4; i++) { af47[i][0] = rdA(4 + i, 0); af47[i][1] = rdA(4 + i, 1); }
        if (pf) stage_tile256(A, ld, row0, (t + 1) * 64, nb, tid);
        __builtin_amdgcn_s_barrier();
        __builtin_amdgcn_s_setprio(1);
#pragma unroll
        for (int i = 0; i < 4; i++)
#pragma unroll
            for (int j = 0; j < 2; j++) {
                acc[i][j] = __builtin_amdgcn_mfma_f32_16x16x32_bf16(af03[i][0], bfr[j][0], acc[i][j], 0, 0, 0);
                acc[i][j] = __builtin_amdgcn_mfma_f32_16x16x32_bf16(af03[i][1], bfr[j][1], acc[i][j], 0, 0, 0);
            }
        __builtin_amdgcn_s_setprio(0);
        __builtin_amdgcn_s_barrier();

        // ---- phase 1: read-free; stage B(t+1); MFMA m4-7 x n0-1 ----
        if (pf) stage_tile256(B, ld, col0, (t + 1) * 64, nb + 32768, tid);
        __builtin_amdgcn_s_barrier();
        __builtin_amdgcn_s_setprio(1);
#pragma unroll
        for (int i = 0; i < 4; i++)
#pragma unroll
            for (int j = 0; j < 2; j++) {
                acc[4 + i][j] = __builtin_amdgcn_mfma_f32_16x16x32_bf16(af47[i][0], bfr[j][0], acc[4 + i][j], 0, 0, 0);
                acc[4 + i][j] = __builtin_amdgcn_mfma_f32_16x16x32_bf16(af47[i][1], bfr[j][1], acc[4 + i][j], 0, 0, 0);
            }
        __builtin_amdgcn_s_setprio(0);
        __builtin_amdgcn_s_barrier();

        // ---- phase 2: read B n2-3; MFMA m4-7 x n2-3 ----
#pragma unroll
        for (int j = 0; j < 2; j++) { bfr[j][0] = rdB(2 + j, 0); bfr[j][1] = rdB(2 + j, 1); }
        __builtin_amdgcn_s_barrier();
        __builtin_amdgcn_s_setprio(1);
#pragma unroll
        for (int i = 0; i < 4; i++)
#pragma unroll
            for (int j = 0; j < 2; j++) {
                acc[4 + i][2 + j] = __builtin_amdgcn_mfma_f32_16x16x32_bf16(af47[i][0], bfr[j][0], acc[4 + i][2 + j], 0, 0, 0);
                acc[4 + i][2 + j] = __builtin_amdgcn_mfma_f32_16x16x32_bf16(af47[i][1], bfr[j][1], acc[4 + i][2 + j], 0, 0, 0);
            }
        __builtin_amdgcn_s_setprio(0);
        __builtin_amdgcn_s_barrier();

        // ---- phase 3: pure-register MFMA m0-3 x n2-3 (af03 still live);
        //      tile-boundary vmcnt (loads are >=2 phases old) + barrier ----
        __builtin_amdgcn_s_setprio(1);
#pragma unroll
        for (int i = 0; i < 4; i++)
#pragma unroll
            for (int j = 0; j < 2; j++) {
                acc[i][2 + j] = __builtin_amdgcn_mfma_f32_16x16x32_bf16(af03[i][0], bfr[j][0], acc[i][2 + j], 0, 0, 0);
                acc[i][2 + j] = __builtin_amdgcn_mfma_f32_16x16x32_bf16(af03[i][1], bfr[j][1], acc[i][2 + j], 0, 0, 0);
            }
        __builtin_amdgcn_s_setprio(0);
        asm volatile("s_waitcnt vmcnt(0)" ::: "memory");
        __builtin_amdgcn_s_barrier();
    }
}

// ---------------------------------------------------------------------------
// Double-buffered 2-phase GEMM core — used by GEMM-C. S windows of BK=32;
// 64B-row LDS; 2-bit slot swizzle (slot ^= row&3) on both sides.
// ---------------------------------------------------------------------------
template<int BM, int BN, int S>
__device__ __forceinline__ void gemm_core_db(const u16* __restrict__ A,
                                             const u16* __restrict__ B,
                                             int Kloop, int ld,
                                             int row0, int col0,
                                             u16* smem,
                                             f32x4 (&acc)[BM / 32][BN / 32])
{
    constexpr int MT = BM / 32, NT = BN / 32;
    constexpr int STG = (BM + BN) * 32;     // u16 per stage
    constexpr int SET = STG * S;            // u16 per buffer set
    const int tid  = threadIdx.x;
    const int lane = tid & 63;
    const int wv   = tid >> 6;
    const int wr   = wv >> 1, wc = wv & 1;
    const int lr   = lane & 15, kg = lane >> 4;

#pragma unroll
    for (int i = 0; i < MT; i++)
#pragma unroll
        for (int j = 0; j < NT; j++) {
            f32x4 z = {0.f, 0.f, 0.f, 0.f};
            acc[i][j] = z;
        }

    auto stage_in = [&](u16* set, int k0) {
#pragma unroll
        for (int c = tid; c < BM * 4; c += 256) {
            int row = c >> 2, sl = swz64(c & 3, row);
            const u16* gA = A + (size_t)(row0 + row) * ld + k0 + sl * 8;
#pragma unroll
            for (int s = 0; s < S; s++)
                async_copy16(set + s * STG + c * 8, gA + s * 32);
        }
#pragma unroll
        for (int c = tid; c < BN * 4; c += 256) {
            int row = c >> 2, sl = swz64(c & 3, row);
            const u16* gB = B + (size_t)(col0 + row) * ld + k0 + sl * 8;
#pragma unroll
            for (int s = 0; s < S; s++)
                async_copy16(set + s * STG + BM * 32 + c * 8, gB + s * 32);
        }
    };

    stage_in(smem, 0);
    __syncthreads();           // drain prologue staging

    int p = 0;
    for (int k0 = 0; k0 < Kloop; k0 += 32 * S) {
        if (k0 + 32 * S < Kloop)
            stage_in(smem + (p ^ 1) * SET, k0 + 32 * S);   // prefetch next window
        u16* set = smem + p * SET;
#pragma unroll
        for (int s = 0; s < S; s++) {
            const u16* sA = set + s * STG;
            const u16* sB = sA + BM * 32;
            bf16x8 af[MT], bfr[NT];
#pragma unroll
            for (int i = 0; i < MT; i++) {
                int row = wr * (BM / 2) + i * 16 + lr;
                af[i] = *(const bf16x8*)(sA + (row * 32 + swz64(kg, row) * 8));
            }
#pragma unroll
            for (int j = 0; j < NT; j++) {
                int row = wc * (BN / 2) + j * 16 + lr;
                bfr[j] = *(const bf16x8*)(sB + (row * 32 + swz64(kg, row) * 8));
            }
#pragma unroll
            for (int i = 0; i < MT; i++)
#pragma unroll
                for (int j = 0; j < NT; j++)
                    acc[i][j] = __builtin_amdgcn_mfma_f32_16x16x32_bf16(
                                    af[i], bfr[j], acc[i][j], 0, 0, 0);
        }
        __syncthreads();       // one barrier/window; vmcnt drain overlapped above
        p ^= 1;
    }
}

// ---------------------------------------------------------------------------
// k_prep: fused independent pre-GEMM work, block-role partitioned.
//   block 0       : conn = sigmoid(relu(na@W1+b1)@W2+b2); wts = softmax(act_w)
//   blocks 1-512  : gate softmax + y = x*gate (bf16)
//   blocks 513-1536: wmT[u, d*4+b] = w[d,u,b]*sigmoid(delay[d,u,b]) (bf16)
// ---------------------------------------------------------------------------
__global__ __launch_bounds__(256)
void k_prep(const float* __restrict__ na, const float* __restrict__ W1,
            const float* __restrict__ b1, const float* __restrict__ W2,
            const float* __restrict__ b2, const float* __restrict__ actw,
            float* __restrict__ conn, float* __restrict__ wts,
            const float* __restrict__ x, const float* __restrict__ gW,
            const float* __restrict__ gb, float* __restrict__ gate,
            u16* __restrict__ y,
            const float* __restrict__ w, const float* __restrict__ delay,
            u16* __restrict__ wmT)
{
    __shared__ __align__(16) char sh[256 * 32 * 4 + 128];
    const int bid = blockIdx.x;
    const int tid = threadIdx.x;

    if (bid == 0) {
        // ---- role: small MLP + act-weight softmax ----
        float* red = (float*)sh;
        float* hsh = (float*)(sh + 256 * 32 * 4);
        float h[32];
#pragma unroll
        for (int k = 0; k < 32; k++) h[k] = 0.f;
        for (int u = tid; u < 2048; u += 256) {
            float nav = na[u];
            const float* row = W1 + u * 32;
#pragma unroll
            for (int k = 0; k < 32; k++) h[k] += nav * row[k];
        }
#pragma unroll
        for (int k = 0; k < 32; k++) red[tid * 32 + k] = h[k];
        for (int s = 128; s > 0; s >>= 1) {
            __syncthreads();
            if (tid < s)
#pragma unroll
                for (int k = 0; k < 32; k++) red[tid * 32 + k] += red[(tid + s) * 32 + k];
        }
        __syncthreads();
        if (tid < 32) hsh[tid] = fmaxf(red[tid] + b1[tid], 0.f);
        if (tid == 0) {
            float e[9], m = -1e30f;
            for (int i = 0; i < 9; i++) { e[i] = actw[i]; m = fmaxf(m, e[i]); }
            float s = 0.f;
            for (int i = 0; i < 9; i++) { e[i] = expf(e[i] - m); s += e[i]; }
            for (int i = 0; i < 9; i++) wts[i] = e[i] / s;
        }
        __syncthreads();
        for (int u = tid; u < 2048; u += 256) {
            float a = 0.f;
#pragma unroll
            for (int k = 0; k < 32; k++) a += hsh[k] * W2[k * 2048 + u];
            conn[u] = 1.f / (1.f + expf(-(a + b2[u])));
        }
    } else if (bid <= 512) {
        // ---- role: gate softmax + y = x*gate ----
        const int lane = tid & 63, wvx = tid >> 6;
        const int n = (bid - 1) * 4 + wvx;
        const float* xr = x + (size_t)n * 1024;
        float a0 = 0, a1 = 0, a2 = 0, a3 = 0;
        float xv[16];
#pragma unroll
        for (int s = 0; s < 16; s++) {
            int d = s * 64 + lane;
            float xd = xr[d]; xv[s] = xd;
            float4 g4 = *(const float4*)(gW + d * 4);
            a0 += xd * g4.x; a1 += xd * g4.y; a2 += xd * g4.z; a3 += xd * g4.w;
        }
#pragma unroll
        for (int off = 32; off > 0; off >>= 1) {
            a0 += __shfl_xor(a0, off); a1 += __shfl_xor(a1, off);
            a2 += __shfl_xor(a2, off); a3 += __shfl_xor(a3, off);
        }
        a0 += gb[0]; a1 += gb[1]; a2 += gb[2]; a3 += gb[3];
        float m = fmaxf(fmaxf(a0, a1), fmaxf(a2, a3));
        float e0 = expf(a0 - m), e1 = expf(a1 - m), e2 = expf(a2 - m), e3 = expf(a3 - m);
        float inv = 1.f / (e0 + e1 + e2 + e3);
        float g0 = e0 * inv, g1 = e1 * inv, g2 = e2 * inv, g3 = e3 * inv;
        if (lane == 0) *(float4*)(gate + n * 4) = make_float4(g0, g1, g2, g3);
#pragma unroll
        for (int s = 0; s < 16; s++) {
            int d = s * 64 + lane;
            ushort4 o;
            o.x = f2b(xv[s] * g0); o.y = f2b(xv[s] * g1);
            o.z = f2b(xv[s] * g2); o.w = f2b(xv[s] * g3);
            *(ushort4*)(y + (size_t)n * 4096 + d * 4) = o;
        }
    } else {
        // ---- role: wmT transpose+cast ----
        typedef ushort4 row65[65];
        row65* tile = (row65*)sh;
        const int b = bid - 513;
        const int u0 = (b & 31) * 64, d0 = (b >> 5) * 32;
        const int tx = tid & 63, ty = tid >> 6;
#pragma unroll
        for (int i = 0; i < 8; i++) {
            int d = i * 4 + ty;
            size_t idx = ((size_t)(d0 + d) * 2048 + (u0 + tx)) * 4;
            float4 w4 = *(const float4*)(w + idx);
            float4 d4 = *(const float4*)(delay + idx);
            ushort4 o;
            o.x = f2b(w4.x / (1.f + expf(-d4.x)));
            o.y = f2b(w4.y / (1.f + expf(-d4.y)));
            o.z = f2b(w4.z / (1.f + expf(-d4.z)));
            o.w = f2b(w4.w / (1.f + expf(-d4.w)));
            tile[d][tx] = o;
        }
        __syncthreads();
        const int dx = tid & 31, uy = tid >> 5;
#pragma unroll
        for (int i = 0; i < 8; i++) {
            int u = i * 8 + uy;
            *(ushort4*)(wmT + (size_t)(u0 + u) * 4096 + (d0 + dx) * 4) = tile[dx][u];
        }
    }
}

// ---------------------------------------------------------------------------
// transpose + cast: in[R,C] f32 -> out[C,R] bf16, 64x64 tiles (rW only)
// ---------------------------------------------------------------------------
__global__ __launch_bounds__(256)
void k_transpose(const float* __restrict__ in, u16* __restrict__ out, int R, int C)
{
    __shared__ __align__(16) u16 t[64][68];
    const int tid = threadIdx.x, tx = tid & 15, ty = tid >> 4;
    const int c0 = blockIdx.x * 64, r0 = blockIdx.y * 64;
#pragma unroll
    for (int i = 0; i < 4; i++) {
        int r = r0 + ty + i * 16;
        float4 v = *(const float4*)(in + (size_t)r * C + c0 + tx * 4);
        t[tx * 4 + 0][ty + i * 16] = f2b(v.x); t[tx * 4 + 1][ty + i * 16] = f2b(v.y);
        t[tx * 4 + 2][ty + i * 16] = f2b(v.z); t[tx * 4 + 3][ty + i * 16] = f2b(v.w);
    }
    __syncthreads();
#pragma unroll
    for (int i = 0; i < 4; i++) {
        int c = ty + i * 16;
        ushort4 v;
        v.x = t[c][tx * 4 + 0]; v.y = t[c][tx * 4 + 1];
        v.z = t[c][tx * 4 + 2]; v.w = t[c][tx * 4 + 3];
        *(ushort4*)(out + (size_t)(c0 + c) * R + r0 + tx * 4) = v;
    }
}

// ---------------------------------------------------------------------------
// 8-way activation blend
// ---------------------------------------------------------------------------
__device__ __forceinline__ float act_blend(float a,
    float w0, float w1, float w2, float w3,
    float w4, float w5, float w6, float w7)
{
    float sig = 1.f / (1.f + expf(-a));
    float elu = (a > 0.f) ? a : (expf(a) - 1.f);
    float th  = tanhf(a);
    float rel = fmaxf(a, 0.f);
    float sil = a * sig;
    float gel = a * 0.5f * (1.f + erff(a * 0.70710678118654752f));
    float sel = (a > 0.f) ? 1.0507009873554805f * a
                          : 1.0507009873554805f * 1.6732632423543772f * (expf(a) - 1.f);
    float sp  = (a > 20.f) ? a : log1pf(expf(a));
    float mish = a * tanhf(sp);
    return w0 * sig + w1 * elu + w2 * th + w3 * rel + w4 * sil + w5 * gel
         + w6 * sel + w7 * mish;
}

// ---------------------------------------------------------------------------
// GEMM-A (4-phase 256^2, split-K): P[z][n,u] partial = y@wmT^T over K-chunk z.
// grid (8, 8, 4), 512 thr, LDS 128 KiB -> 256 blocks, 1/CU.
// ---------------------------------------------------------------------------
__global__ __launch_bounds__(512, 2)
void k_gemm_a8(const u16* __restrict__ A, const u16* __restrict__ B,
               float* __restrict__ P)
{
    __shared__ __align__(16) char lds[131072];
    const int row0 = blockIdx.y * 256, col0 = blockIdx.x * 256;
    const u16* Ac = A + (size_t)blockIdx.z * 1024;
    const u16* Bc = B + (size_t)blockIdx.z * 1024;

    f32x4 acc[8][4];
    gemm256_core8(Ac, Bc, 16, 4096, row0, col0, lds, acc);

    float* Pz = P + (size_t)blockIdx.z * 2048 * 2048;
    const int tid = threadIdx.x, lane = tid & 63, wv = tid >> 6;
    const int wr = wv >> 2, wc = wv & 3, lr = lane & 15, kg = lane >> 4;
#pragma unroll
    for (int i = 0; i < 8; i++)
#pragma unroll
        for (int r = 0; r < 4; r++) {
            int n = row0 + wr * 128 + i * 16 + kg * 4 + r;
            size_t ob = (size_t)n * 2048;
#pragma unroll
            for (int j = 0; j < 4; j++)
                Pz[ob + col0 + wc * 64 + j * 16 + lr] = acc[i][j][r];
        }
}

// ---------------------------------------------------------------------------
// reduce 4 split-K partials + GEMM-A epilogue:
// blend[n,u] = blend8(relu((sum_s P[s][n,u] + gate[n]·b[u])*conn[u]*mask[u]))
// ---------------------------------------------------------------------------
__global__ __launch_bounds__(256)
void k_reduce_blend(const float* __restrict__ P, const float* __restrict__ gate,
                    const float* __restrict__ conn, const float* __restrict__ mask,
                    const float* __restrict__ wts, const float* __restrict__ bbias,
                    u16* __restrict__ blend)
{
    constexpr size_t SL = (size_t)2048 * 2048;
    const int n  = blockIdx.x;
    const int u0 = threadIdx.x * 8;
    const float* base = P + (size_t)n * 2048 + u0;

    float v[8];
#pragma unroll
    for (int h = 0; h < 2; h++) {
        float4 a = *(const float4*)(base + h * 4);
        float4 b = *(const float4*)(base + SL + h * 4);
        float4 c = *(const float4*)(base + 2 * SL + h * 4);
        float4 d = *(const float4*)(base + 3 * SL + h * 4);
        v[h * 4 + 0] = a.x + b.x + c.x + d.x;
        v[h * 4 + 1] = a.y + b.y + c.y + d.y;
        v[h * 4 + 2] = a.z + b.z + c.z + d.z;
        v[h * 4 + 3] = a.w + b.w + c.w + d.w;
    }
    float4 g = *(const float4*)(gate + n * 4);
    const float w0 = wts[0], w1 = wts[1], w2 = wts[2], w3 = wts[3];
    const float w4 = wts[4], w5 = wts[5], w6 = wts[6], w7 = wts[7];

    ushort4 o[2];
#pragma unroll
    for (int j = 0; j < 8; j++) {
        int u = u0 + j;
        float4 b4 = *(const float4*)(bbias + u * 4);
        float z = v[j] + g.x * b4.x + g.y * b4.y + g.z * b4.z + g.w * b4.w;
        float a = fmaxf(z * conn[u] * mask[u], 0.f);
        u16 r = f2b(act_blend(a, w0, w1, w2, w3, w4, w5, w6, w7));
        ((u16*)o)[j] = r;
    }
    *(ushort4*)(blend + (size_t)n * 2048 + u0)     = o[0];
    *(ushort4*)(blend + (size_t)n * 2048 + u0 + 4) = o[1];
}

// ---------------------------------------------------------------------------
// GEMM-B (4-phase 256^2): logits[n,m] = blend@read_W^T + read_b (bf16 out)
// grid (32, 8), 512 thr -> 256 blocks, 1/CU.
// ---------------------------------------------------------------------------
__global__ __launch_bounds__(512, 2)
void k_gemm_logits8(const u16* __restrict__ BL, const u16* __restrict__ RWT,
                    const float* __restrict__ rbias, u16* __restrict__ out)
{
    __shared__ __align__(16) char lds[131072];
    const int row0 = blockIdx.y * 256, col0 = blockIdx.x * 256;

    f32x4 acc[8][4];
    gemm256_core8(BL, RWT, 32, 2048, row0, col0, lds, acc);

    const int tid = threadIdx.x, lane = tid & 63, wv = tid >> 6;
    const int wr = wv >> 2, wc = wv & 3, lr = lane & 15, kg = lane >> 4;
    float rb[4]; int mm[4];
#pragma unroll
    for (int j = 0; j < 4; j++) {
        mm[j] = col0 + wc * 64 + j * 16 + lr;
        rb[j] = rbias[mm[j]];
    }
#pragma unroll
    for (int i = 0; i < 8; i++)
#pragma unroll
        for (int r = 0; r < 4; r++) {
            int n = row0 + wr * 128 + i * 16 + kg * 4 + r;
            size_t ob = (size_t)n * 8192;
#pragma unroll
            for (int j = 0; j < 4; j++)
                out[ob + mm[j]] = f2b(acc[i][j][r] + rb[j]);
        }
}

// ---------------------------------------------------------------------------
// k_post: fused softmax(logits) ∥ transpose(mem -> memT).
//   blocks 0-2047   : in-place row softmax over 8192 bf16
//   blocks 2048-4095: mem[8192,1024] f32 -> memT[1024,8192] bf16
// ---------------------------------------------------------------------------
__global__ __launch_bounds__(256)
void k_post(u16* __restrict__ buf, const float* __restrict__ mem,
            u16* __restrict__ memT)
{
    __shared__ __align__(16) char sh[64 * 68 * 2 + 64];
    const int bid = blockIdx.x;
    const int tid = threadIdx.x;

    if (bid < 2048) {
        float* red = (float*)sh;
        const int lane = tid & 63, wv = tid >> 6;
        u16* row = buf + (size_t)bid * 8192;
        float v[32];
        float mx = -1e30f;
#pragma unroll
        for (int s = 0; s < 8; s++) {
            ushort4 u4 = *(const ushort4*)(row + (s * 256 + tid) * 4);
            float a = b2f(u4.x), b = b2f(u4.y), c = b2f(u4.z), d = b2f(u4.w);
            v[s * 4 + 0] = a; v[s * 4 + 1] = b; v[s * 4 + 2] = c; v[s * 4 + 3] = d;
            mx = fmaxf(mx, fmaxf(fmaxf(a, b), fmaxf(c, d)));
        }
#pragma unroll
        for (int off = 32; off > 0; off >>= 1) mx = fmaxf(mx, __shfl_xor(mx, off));
        if (lane == 0) red[wv] = mx;
        __syncthreads();
        mx = fmaxf(fmaxf(red[0], red[1]), fmaxf(red[2], red[3]));
        float sum = 0.f;
#pragma unroll
        for (int k = 0; k < 32; k++) { v[k] = expf(v[k] - mx); sum += v[k]; }
#pragma unroll
        for (int off = 32; off > 0; off >>= 1) sum += __shfl_xor(sum, off);
        if (lane == 0) red[4 + wv] = sum;
        __syncthreads();
        float inv = 1.f / (red[4] + red[5] + red[6] + red[7]);
#pragma unroll
        for (int s = 0; s < 8; s++) {
            ushort4 o;
            o.x = f2b(v[s * 4 + 0] * inv); o.y = f2b(v[s * 4 + 1] * inv);
            o.z = f2b(v[s * 4 + 2] * inv); o.w = f2b(v[s * 4 + 3] * inv);
            *(ushort4*)(row + (s * 256 + tid) * 4) = o;
        }
    } else {
        typedef u16 row68[68];
        row68* t = (row68*)sh;
        const int b = bid - 2048;
        const int c0 = (b & 15) * 64, r0 = (b >> 4) * 64;   // C=1024, R=8192
        const int tx = tid & 15, ty = tid >> 4;
#pragma unroll
        for (int i = 0; i < 4; i++) {
            int r = r0 + ty + i * 16;
            float4 v = *(const float4*)(mem + (size_t)r * 1024 + c0 + tx * 4);
            t[tx * 4 + 0][ty + i * 16] = f2b(v.x); t[tx * 4 + 1][ty + i * 16] = f2b(v.y);
            t[tx * 4 + 2][ty + i * 16] = f2b(v.z); t[tx * 4 + 3][ty + i * 16] = f2b(v.w);
        }
        __syncthreads();
#pragma unroll
        for (int i = 0; i < 4; i++) {
            int c = ty + i * 16;
            ushort4 v;
            v.x = t[c][tx * 4 + 0]; v.y = t[c][tx * 4 + 1];
            v.z = t[c][tx * 4 + 2]; v.w = t[c][tx * 4 + 3];
            *(ushort4*)(memT + (size_t)(c0 + c) * 8192 + r0 + tx * 4) = v;
        }
    }
}

// ---------------------------------------------------------------------------
// GEMM-C (2-phase 128^2 split-K, S=2): P[z][n,md] partial = attn @ mem chunk.
// ---------------------------------------------------------------------------
template<int BM, int BN, int S, int NCOL>
__global__ __launch_bounds__(256, 4)
void k_gemm_partial(const u16* __restrict__ A, const u16* __restrict__ B,
                    int Kchunk, int ld, float* __restrict__ P)
{
    constexpr int MT = BM / 32, NT = BN / 32;
    __shared__ __align__(16) u16 smem[2 * (BM + BN) * 32 * S];

    const int nx = gridDim.x, ny = gridDim.y;
    const int f  = blockIdx.x + nx * blockIdx.y;
    const int ch = (nx * ny) >> 3;                 // chunk per XCD
    const int sw = (f & 7) * ch + (f >> 3);        // bijective (nwg%8==0)
    const int bx = sw % nx, by = sw / nx;
    const int row0 = by * BM, col0 = bx * BN;

    const u16* Ac = A + (size_t)blockIdx.z * Kchunk;
    const u16* Bc = B + (size_t)blockIdx.z * Kchunk;

    f32x4 acc[MT][NT];
    gemm_core_db<BM, BN, S>(Ac, Bc, Kchunk, ld, row0, col0, smem, acc);

    float* Pz = P + (size_t)blockIdx.z * 2048 * NCOL;
    const int tid = threadIdx.x, lane = tid & 63, wv = tid >> 6;
    const int wr = wv >> 1, wc = wv & 1, lr = lane & 15, kg = lane >> 4;
#pragma unroll
    for (int i = 0; i < MT; i++)
#pragma unroll
        for (int r = 0; r < 4; r++) {
            int n = row0 + wr * (BM / 2) + i * 16 + kg * 4 + r;
            size_t ob = (size_t)n * NCOL;
#pragma unroll
            for (int j = 0; j < NT; j++)
                Pz[ob + col0 + wc * (BN / 2) + j * 16 + lr] = acc[i][j][r];
        }
}

// ---------------------------------------------------------------------------
// reduce 4 split-K partials into final f32 output (GEMM-C tail)
// ---------------------------------------------------------------------------
__global__ __launch_bounds__(256)
void k_reduce_out(const float* __restrict__ P, float* __restrict__ out)
{
    constexpr size_t SL = (size_t)2048 * 1024;
    size_t i = ((size_t)blockIdx.x * 256 + threadIdx.x) * 4;
    float4 a = *(const float4*)(P + i);
    float4 b = *(const float4*)(P + SL + i);
    float4 c = *(const float4*)(P + 2 * SL + i);
    float4 d = *(const float4*)(P + 3 * SL + i);
    float4 o;
    o.x = a.x + b.x + c.x + d.x;
    o.y = a.y + b.y + c.y + d.y;
    o.z = a.z + b.z + c.z + d.z;
    o.w = a.w + b.w + c.w + d.w;
    *(float4*)(out + i) = o;
}

// sentinel: distinctive output if workspace is too small (absmax ~12345)
__global__ void k_fill(float* out, int n)
{
    int i = blockIdx.x * 256 + threadIdx.x;
    if (i < n) out[i] = 12345.f;
}

// ---------------------------------------------------------------------------
extern "C" void kernel_launch(void* const* d_in, const int* in_sizes, int n_in,
                              void* d_out, int out_size, void* d_ws, size_t ws_size,
                              hipStream_t stream)
{
    const float* x     = (const float*)d_in[0];
    const float* w     = (const float*)d_in[1];
    const float* delay = (const float*)d_in[2];
    const float* bb    = (const float*)d_in[3];
    const float* gW    = (const float*)d_in[4];
    const float* gb    = (const float*)d_in[5];
    const float* na    = (const float*)d_in[6];
    const float* cW1   = (const float*)d_in[7];
    const float* cb1   = (const float*)d_in[8];
    const float* cW2   = (const float*)d_in[9];
    const float* cb2   = (const float*)d_in[10];
    const float* mask  = (const float*)d_in[11];
    const float* actw  = (const float*)d_in[12];
    const float* rW    = (const float*)d_in[13];
    const float* rb    = (const float*)d_in[14];
    const float* mem   = (const float*)d_in[15];
    (void)in_sizes; (void)n_in;

    char* ws = (char*)d_ws;
    size_t off = 0;
    auto alloc = [&](size_t bytes) {
        size_t o = off; off += (bytes + 255) & ~(size_t)255; return o;
    };
    size_t o_wts   = alloc(9 * 4);
    size_t o_gate  = alloc(2048 * 4 * 4);
    size_t o_conn  = alloc(2048 * 4);
    size_t o_y     = alloc((size_t)2048 * 4096 * 2);   // y; later aliased as memT
    size_t o_wmT   = alloc((size_t)2048 * 4096 * 2);
    size_t o_blend = alloc((size_t)2048 * 2048 * 2);
    size_t o_rwT   = alloc((size_t)8192 * 2048 * 2);   // rwT; also split-K partials
    size_t o_log   = alloc((size_t)2048 * 8192 * 2);   // logits; A-partials overflow

    if (off > ws_size) {   // loud, distinguishable failure mode
        k_fill<<<(out_size + 255) / 256, 256, 0, stream>>>((float*)d_out, out_size);
        return;
    }

    float* wts   = (float*)(ws + o_wts);
    float* gate  = (float*)(ws + o_gate);
    float* conn  = (float*)(ws + o_conn);
    u16* y       = (u16*)(ws + o_y);
    u16* wmT     = (u16*)(ws + o_wmT);
    u16* blend   = (u16*)(ws + o_blend);
    u16* rwT     = (u16*)(ws + o_rwT);
    u16* logits  = (u16*)(ws + o_log);
    u16* memT    = y;   // y dead after GEMM-A; same size (16 MB)

    // split-K partial buffers, aliased into lifetime holes:
    //   A-partials: 4 x 2048 x 2048 f32 = 64 MB @ [o_rwT, o_rwT+64MB)
    //     (rwT written AFTER reduce_blend; logits written AFTER that).
    //   C-partials: 4 x 2048 x 1024 f32 = 32 MB @ o_rwT (rwT dead after logits).
    float* pA = (float*)(ws + o_rwT);
    float* pC = (float*)(ws + o_rwT);

    // prep: small MLP ∥ gate+y ∥ wmT  (1 + 512 + 1024 blocks)
    k_prep<<<1537, 256, 0, stream>>>(na, cW1, cb1, cW2, cb2, actw, conn, wts,
                                     x, gW, gb, gate, y, w, delay, wmT);

    // GEMM-A: partials = y[2048,4096] @ wmT[2048,4096]^T, split-K=4 (K=1024 each)
    k_gemm_a8<<<dim3(8, 8, 4), 512, 0, stream>>>(y, wmT, pA);
    k_reduce_blend<<<2048, 256, 0, stream>>>(pA, gate, conn, mask, wts, bb, blend);

    k_transpose<<<dim3(128, 32), 256, 0, stream>>>(rW, rwT, 2048, 8192);
    k_gemm_logits8<<<dim3(32, 8), 512, 0, stream>>>(blend, rwT, rb, logits);

    // softmax(logits) ∥ transpose(mem -> memT)
    k_post<<<4096, 256, 0, stream>>>(logits, mem, memT);

    // GEMM-C: out-partials = attn[2048,8192] @ memT[1024,8192]^T, split-K=4 (K=2048)
    k_gemm_partial<128, 128, 2, 1024><<<dim3(8, 16, 4), 256, 0, stream>>>(
        logits, memT, 2048, 8192, pC);
    k_reduce_out<<<2048, 256, 0, stream>>>(pC, (float*)d_out);
}

// Round 9
// 416.441 us; speedup vs baseline: 1.0951x; 1.0022x over previous
//
#include <hip/hip_runtime.h>

// ============================================================================
// PlasticityModelMoE — MI355X (gfx950). Inputs f32, output f32, bf16 MFMA.
// R16: workspace restructure with graceful fallback (cores frozen at R15):
//   Plan B (if ws_size fits +64MB partial pool):
//    - A-partials get a DEDICATED pool (no rwT aliasing) -> transpose(rW)
//      loses its false dependency and fuses into k_prep as block-role 4
//      (runs concurrently with gate_y/wmT; 19us off the critical path).
//    - GEMM-C moves to the proven 256^2 4-phase core, split-K=8
//      (grid 4x8x8 = 256 blocks, Kchunk=1024 = 16 Ktiles — a8's exact
//      config); partials reuse the pool (dead after reduce_blend);
//      8-slice reduce_out.
//   Plan A (fallback): byte-identical R15 schedule (aliased partials,
//      standalone transpose, 128^2 2-phase GEMM-C). No sentinel risk.
// ============================================================================

typedef unsigned short u16;
typedef __attribute__((ext_vector_type(8))) short bf16x8;   // 8 bf16 = 4 VGPRs
typedef __attribute__((ext_vector_type(4))) float f32x4;

__device__ __forceinline__ float b2f(u16 h) {
    union { unsigned u; float f; } v; v.u = ((unsigned)h) << 16; return v.f;
}
__device__ __forceinline__ u16 f2b(float f) {
    union { float f; unsigned u; } v; v.f = f;
    unsigned u = v.u;
    return (u16)((u + 0x7fffu + ((u >> 16) & 1u)) >> 16);   // round-nearest-even
}

// async global->LDS, 16B per lane (wave-uniform base + lane*16 — m97 pattern).
__device__ __forceinline__ void async_copy16(void* lds, const void* g) {
    __builtin_amdgcn_global_load_lds(
        (__attribute__((address_space(1))) void*)(g),
        (__attribute__((address_space(3))) void*)(lds), 16, 0, 0);
}

// 3-bit swizzle for 128B-row tiles: 16B-slot bits [6:4] ^= row bits [9:7].
// Involution; conflict-free ds_read_b128 (R11: BANK_CONFLICT -> 0).
__device__ __forceinline__ int swz(int o) { return o ^ (((o >> 7) & 7) << 4); }

// 2-bit swizzle for 64B-row tiles (2-phase core): slot ^= row&3. 8way->4way.
__device__ __forceinline__ int swz64(int kg, int row) { return kg ^ (row & 3); }

// ---------------------------------------------------------------------------
// 256x256 4-phase/7-barrier GEMM core (R15-proven). C = A[256,K]*B[256,K]^T.
// 512 thr / 8 waves as 2(M) x 4(N); per-wave 128x64; acc[8][4] f32x4.
// lds: 128 KiB = 2 bufs x { A: 2x(128x64) halves, B: same } bf16, swizzled.
// Ktiles = K/64 (>=2). ld = row stride of A and B in elements.
// ---------------------------------------------------------------------------
__device__ __forceinline__ void stage_tile256(const u16* __restrict__ src, int ld,
                                              int base0, int k0,
                                              char* ldsbase, int tid)
{
#pragma unroll
    for (int h = 0; h < 2; h++)
#pragma unroll
        for (int it = 0; it < 2; it++) {
            int o = it * 8192 + tid * 16;          // linear LDS byte offset
            int s = swz(o);                        // logical source offset
            int r = s >> 7;                        // row within 128-row half
            int c = (s & 127) >> 1;                // bf16 col (multiple of 8)
            async_copy16(ldsbase + h * 16384 + o,
                         src + (size_t)(base0 + h * 128 + r) * ld + k0 + c);
        }
}

__device__ __forceinline__ void gemm256_core8(const u16* __restrict__ A,
                                              const u16* __restrict__ B,
                                              int Ktiles, int ld,
                                              int row0, int col0,
                                              char* lds, f32x4 (&acc)[8][4])
{
    const int tid  = threadIdx.x;
    const int lane = tid & 63;
    const int wv   = tid >> 6;
    const int wr   = wv >> 2;          // 0..1  (M half)
    const int wc   = wv & 3;           // 0..3  (N quarter)
    const int lr   = lane & 15, kg = lane >> 4;

#pragma unroll
    for (int i = 0; i < 8; i++)
#pragma unroll
        for (int j = 0; j < 4; j++) {
            f32x4 z = {0.f, 0.f, 0.f, 0.f};
            acc[i][j] = z;
        }

    // prologue: stage tile 0 into buf 0
    stage_tile256(A, ld, row0, 0, lds, tid);
    stage_tile256(B, ld, col0, 0, lds + 32768, tid);
    asm volatile("s_waitcnt vmcnt(0)" ::: "memory");
    __builtin_amdgcn_s_barrier();

    bf16x8 af03[4][2], af47[4][2], bfr[2][2];

    for (int t = 0; t < Ktiles; t++) {
        const int buf = (t & 1) << 16;
        const char* sA = lds + buf + wr * 16384;
        const char* sB = lds + buf + 32768 + ((wc >> 1) * 16384);
        char* nb = lds + (((t + 1) & 1) << 16);
        const bool pf = (t + 1 < Ktiles);

        auto rdA = [&](int i, int ks) {
            int off = (i * 16 + lr) * 128 + ks * 64 + kg * 16;
            return *(const bf16x8*)(sA + swz(off));
        };
        auto rdB = [&](int j, int ks) {
            int off = ((wc & 1) * 64 + j * 16 + lr) * 128 + ks * 64 + kg * 16;
            return *(const bf16x8*)(sB + swz(off));
        };

        // ---- phase 0: read af03 + b01, THEN af47 (counted lgkm before MFMA;
        //      af47 service overlaps ph0 MFMA); stage A(t+1); MFMA m0-3 x n0-1
#pragma unroll
        for (int i = 0; i < 4; i++) { af03[i][0] = rdA(i, 0); af03[i][1] = rdA(i, 1); }
#pragma unroll
        for (int j = 0; j < 2; j++) { bfr[j][0] = rdB(j, 0); bfr[j][1] = rdB(j, 1); }
#pragma unroll
        for (int i = 0; i < 4; i++) { af47[i][0] = rdA(4 + i, 0); af47[i][1] = rdA(4 + i, 1); }
        if (pf) stage_tile256(A, ld, row0, (t + 1) * 64, nb, tid);
        __builtin_amdgcn_s_barrier();
        __builtin_amdgcn_s_setprio(1);
#pragma unroll
        for (int i = 0; i < 4; i++)
#pragma unroll
            for (int j = 0; j < 2; j++) {
                acc[i][j] = __builtin_amdgcn_mfma_f32_16x16x32_bf16(af03[i][0], bfr[j][0], acc[i][j], 0, 0, 0);
                acc[i][j] = __builtin_amdgcn_mfma_f32_16x16x32_bf16(af03[i][1], bfr[j][1], acc[i][j], 0, 0, 0);
            }
        __builtin_amdgcn_s_setprio(0);
        __builtin_amdgcn_s_barrier();

        // ---- phase 1: read-free; stage B(t+1); MFMA m4-7 x n0-1 ----
        if (pf) stage_tile256(B, ld, col0, (t + 1) * 64, nb + 32768, tid);
        __builtin_amdgcn_s_barrier();
        __builtin_amdgcn_s_setprio(1);
#pragma unroll
        for (int i = 0; i < 4; i++)
#pragma unroll
            for (int j = 0; j < 2; j++) {
                acc[4 + i][j] = __builtin_amdgcn_mfma_f32_16x16x32_bf16(af47[i][0], bfr[j][0], acc[4 + i][j], 0, 0, 0);
                acc[4 + i][j] = __builtin_amdgcn_mfma_f32_16x16x32_bf16(af47[i][1], bfr[j][1], acc[4 + i][j], 0, 0, 0);
            }
        __builtin_amdgcn_s_setprio(0);
        __builtin_amdgcn_s_barrier();

        // ---- phase 2: read B n2-3; MFMA m4-7 x n2-3 ----
#pragma unroll
        for (int j = 0; j < 2; j++) { bfr[j][0] = rdB(2 + j, 0); bfr[j][1] = rdB(2 + j, 1); }
        __builtin_amdgcn_s_barrier();
        __builtin_amdgcn_s_setprio(1);
#pragma unroll
        for (int i = 0; i < 4; i++)
#pragma unroll
            for (int j = 0; j < 2; j++) {
                acc[4 + i][2 + j] = __builtin_amdgcn_mfma_f32_16x16x32_bf16(af47[i][0], bfr[j][0], acc[4 + i][2 + j], 0, 0, 0);
                acc[4 + i][2 + j] = __builtin_amdgcn_mfma_f32_16x16x32_bf16(af47[i][1], bfr[j][1], acc[4 + i][2 + j], 0, 0, 0);
            }
        __builtin_amdgcn_s_setprio(0);
        __builtin_amdgcn_s_barrier();

        // ---- phase 3: pure-register MFMA m0-3 x n2-3 (af03 still live);
        //      tile-boundary vmcnt (loads are >=2 phases old) + barrier ----
        __builtin_amdgcn_s_setprio(1);
#pragma unroll
        for (int i = 0; i < 4; i++)
#pragma unroll
            for (int j = 0; j < 2; j++) {
                acc[i][2 + j] = __builtin_amdgcn_mfma_f32_16x16x32_bf16(af03[i][0], bfr[j][0], acc[i][2 + j], 0, 0, 0);
                acc[i][2 + j] = __builtin_amdgcn_mfma_f32_16x16x32_bf16(af03[i][1], bfr[j][1], acc[i][2 + j], 0, 0, 0);
            }
        __builtin_amdgcn_s_setprio(0);
        asm volatile("s_waitcnt vmcnt(0)" ::: "memory");
        __builtin_amdgcn_s_barrier();
    }
}

// ---------------------------------------------------------------------------
// Double-buffered 2-phase GEMM core — fallback GEMM-C. S windows of BK=32;
// 64B-row LDS; 2-bit slot swizzle (slot ^= row&3) on both sides.
// ---------------------------------------------------------------------------
template<int BM, int BN, int S>
__device__ __forceinline__ void gemm_core_db(const u16* __restrict__ A,
                                             const u16* __restrict__ B,
                                             int Kloop, int ld,
                                             int row0, int col0,
                                             u16* smem,
                                             f32x4 (&acc)[BM / 32][BN / 32])
{
    constexpr int MT = BM / 32, NT = BN / 32;
    constexpr int STG = (BM + BN) * 32;     // u16 per stage
    constexpr int SET = STG * S;            // u16 per buffer set
    const int tid  = threadIdx.x;
    const int lane = tid & 63;
    const int wv   = tid >> 6;
    const int wr   = wv >> 1, wc = wv & 1;
    const int lr   = lane & 15, kg = lane >> 4;

#pragma unroll
    for (int i = 0; i < MT; i++)
#pragma unroll
        for (int j = 0; j < NT; j++) {
            f32x4 z = {0.f, 0.f, 0.f, 0.f};
            acc[i][j] = z;
        }

    auto stage_in = [&](u16* set, int k0) {
#pragma unroll
        for (int c = tid; c < BM * 4; c += 256) {
            int row = c >> 2, sl = swz64(c & 3, row);
            const u16* gA = A + (size_t)(row0 + row) * ld + k0 + sl * 8;
#pragma unroll
            for (int s = 0; s < S; s++)
                async_copy16(set + s * STG + c * 8, gA + s * 32);
        }
#pragma unroll
        for (int c = tid; c < BN * 4; c += 256) {
            int row = c >> 2, sl = swz64(c & 3, row);
            const u16* gB = B + (size_t)(col0 + row) * ld + k0 + sl * 8;
#pragma unroll
            for (int s = 0; s < S; s++)
                async_copy16(set + s * STG + BM * 32 + c * 8, gB + s * 32);
        }
    };

    stage_in(smem, 0);
    __syncthreads();           // drain prologue staging

    int p = 0;
    for (int k0 = 0; k0 < Kloop; k0 += 32 * S) {
        if (k0 + 32 * S < Kloop)
            stage_in(smem + (p ^ 1) * SET, k0 + 32 * S);   // prefetch next window
        u16* set = smem + p * SET;
#pragma unroll
        for (int s = 0; s < S; s++) {
            const u16* sA = set + s * STG;
            const u16* sB = sA + BM * 32;
            bf16x8 af[MT], bfr[NT];
#pragma unroll
            for (int i = 0; i < MT; i++) {
                int row = wr * (BM / 2) + i * 16 + lr;
                af[i] = *(const bf16x8*)(sA + (row * 32 + swz64(kg, row) * 8));
            }
#pragma unroll
            for (int j = 0; j < NT; j++) {
                int row = wc * (BN / 2) + j * 16 + lr;
                bfr[j] = *(const bf16x8*)(sB + (row * 32 + swz64(kg, row) * 8));
            }
#pragma unroll
            for (int i = 0; i < MT; i++)
#pragma unroll
                for (int j = 0; j < NT; j++)
                    acc[i][j] = __builtin_amdgcn_mfma_f32_16x16x32_bf16(
                                    af[i], bfr[j], acc[i][j], 0, 0, 0);
        }
        __syncthreads();       // one barrier/window; vmcnt drain overlapped above
        p ^= 1;
    }
}

// ---------------------------------------------------------------------------
// k_prep: fused independent pre-GEMM work, block-role partitioned.
//   block 0        : conn = sigmoid(relu(na@W1+b1)@W2+b2); wts = softmax(act_w)
//   blocks 1-512   : gate softmax + y = x*gate (bf16)
//   blocks 513-1536: wmT[u, d*4+b] = w[d,u,b]*sigmoid(delay[d,u,b]) (bf16)
//   blocks 1537+   : rW[2048,8192] f32 -> rwT[8192,2048] bf16 (plan B only;
//                    4096 blocks — plan A launches 1537 so role 4 never runs)
// ---------------------------------------------------------------------------
__global__ __launch_bounds__(256)
void k_prep(const float* __restrict__ na, const float* __restrict__ W1,
            const float* __restrict__ b1, const float* __restrict__ W2,
            const float* __restrict__ b2, const float* __restrict__ actw,
            float* __restrict__ conn, float* __restrict__ wts,
            const float* __restrict__ x, const float* __restrict__ gW,
            const float* __restrict__ gb, float* __restrict__ gate,
            u16* __restrict__ y,
            const float* __restrict__ w, const float* __restrict__ delay,
            u16* __restrict__ wmT,
            const float* __restrict__ rW, u16* __restrict__ rwT)
{
    __shared__ __align__(16) char sh[256 * 32 * 4 + 128];
    const int bid = blockIdx.x;
    const int tid = threadIdx.x;

    if (bid == 0) {
        // ---- role: small MLP + act-weight softmax ----
        float* red = (float*)sh;
        float* hsh = (float*)(sh + 256 * 32 * 4);
        float h[32];
#pragma unroll
        for (int k = 0; k < 32; k++) h[k] = 0.f;
        for (int u = tid; u < 2048; u += 256) {
            float nav = na[u];
            const float* row = W1 + u * 32;
#pragma unroll
            for (int k = 0; k < 32; k++) h[k] += nav * row[k];
        }
#pragma unroll
        for (int k = 0; k < 32; k++) red[tid * 32 + k] = h[k];
        for (int s = 128; s > 0; s >>= 1) {
            __syncthreads();
            if (tid < s)
#pragma unroll
                for (int k = 0; k < 32; k++) red[tid * 32 + k] += red[(tid + s) * 32 + k];
        }
        __syncthreads();
        if (tid < 32) hsh[tid] = fmaxf(red[tid] + b1[tid], 0.f);
        if (tid == 0) {
            float e[9], m = -1e30f;
            for (int i = 0; i < 9; i++) { e[i] = actw[i]; m = fmaxf(m, e[i]); }
            float s = 0.f;
            for (int i = 0; i < 9; i++) { e[i] = expf(e[i] - m); s += e[i]; }
            for (int i = 0; i < 9; i++) wts[i] = e[i] / s;
        }
        __syncthreads();
        for (int u = tid; u < 2048; u += 256) {
            float a = 0.f;
#pragma unroll
            for (int k = 0; k < 32; k++) a += hsh[k] * W2[k * 2048 + u];
            conn[u] = 1.f / (1.f + expf(-(a + b2[u])));
        }
    } else if (bid <= 512) {
        // ---- role: gate softmax + y = x*gate ----
        const int lane = tid & 63, wvx = tid >> 6;
        const int n = (bid - 1) * 4 + wvx;
        const float* xr = x + (size_t)n * 1024;
        float a0 = 0, a1 = 0, a2 = 0, a3 = 0;
        float xv[16];
#pragma unroll
        for (int s = 0; s < 16; s++) {
            int d = s * 64 + lane;
            float xd = xr[d]; xv[s] = xd;
            float4 g4 = *(const float4*)(gW + d * 4);
            a0 += xd * g4.x; a1 += xd * g4.y; a2 += xd * g4.z; a3 += xd * g4.w;
        }
#pragma unroll
        for (int off = 32; off > 0; off >>= 1) {
            a0 += __shfl_xor(a0, off); a1 += __shfl_xor(a1, off);
            a2 += __shfl_xor(a2, off); a3 += __shfl_xor(a3, off);
        }
        a0 += gb[0]; a1 += gb[1]; a2 += gb[2]; a3 += gb[3];
        float m = fmaxf(fmaxf(a0, a1), fmaxf(a2, a3));
        float e0 = expf(a0 - m), e1 = expf(a1 - m), e2 = expf(a2 - m), e3 = expf(a3 - m);
        float inv = 1.f / (e0 + e1 + e2 + e3);
        float g0 = e0 * inv, g1 = e1 * inv, g2 = e2 * inv, g3 = e3 * inv;
        if (lane == 0) *(float4*)(gate + n * 4) = make_float4(g0, g1, g2, g3);
#pragma unroll
        for (int s = 0; s < 16; s++) {
            int d = s * 64 + lane;
            ushort4 o;
            o.x = f2b(xv[s] * g0); o.y = f2b(xv[s] * g1);
            o.z = f2b(xv[s] * g2); o.w = f2b(xv[s] * g3);
            *(ushort4*)(y + (size_t)n * 4096 + d * 4) = o;
        }
    } else if (bid <= 1536) {
        // ---- role: wmT transpose+cast ----
        typedef ushort4 row65[65];
        row65* tile = (row65*)sh;
        const int b = bid - 513;
        const int u0 = (b & 31) * 64, d0 = (b >> 5) * 32;
        const int tx = tid & 63, ty = tid >> 6;
#pragma unroll
        for (int i = 0; i < 8; i++) {
            int d = i * 4 + ty;
            size_t idx = ((size_t)(d0 + d) * 2048 + (u0 + tx)) * 4;
            float4 w4 = *(const float4*)(w + idx);
            float4 d4 = *(const float4*)(delay + idx);
            ushort4 o;
            o.x = f2b(w4.x / (1.f + expf(-d4.x)));
            o.y = f2b(w4.y / (1.f + expf(-d4.y)));
            o.z = f2b(w4.z / (1.f + expf(-d4.z)));
            o.w = f2b(w4.w / (1.f + expf(-d4.w)));
            tile[d][tx] = o;
        }
        __syncthreads();
        const int dx = tid & 31, uy = tid >> 5;
#pragma unroll
        for (int i = 0; i < 8; i++) {
            int u = i * 8 + uy;
            *(ushort4*)(wmT + (size_t)(u0 + u) * 4096 + (d0 + dx) * 4) = tile[dx][u];
        }
    } else {
        // ---- role (plan B): rW[2048,8192] f32 -> rwT[8192,2048] bf16 ----
        typedef u16 row68[68];
        row68* t = (row68*)sh;
        const int b = bid - 1537;
        const int c0 = (b & 127) * 64, r0 = (b >> 7) * 64;   // C=8192, R=2048
        const int tx = tid & 15, ty = tid >> 4;
#pragma unroll
        for (int i = 0; i < 4; i++) {
            int r = r0 + ty + i * 16;
            float4 v = *(const float4*)(rW + (size_t)r * 8192 + c0 + tx * 4);
            t[tx * 4 + 0][ty + i * 16] = f2b(v.x); t[tx * 4 + 1][ty + i * 16] = f2b(v.y);
            t[tx * 4 + 2][ty + i * 16] = f2b(v.z); t[tx * 4 + 3][ty + i * 16] = f2b(v.w);
        }
        __syncthreads();
#pragma unroll
        for (int i = 0; i < 4; i++) {
            int c = ty + i * 16;
            ushort4 v;
            v.x = t[c][tx * 4 + 0]; v.y = t[c][tx * 4 + 1];
            v.z = t[c][tx * 4 + 2]; v.w = t[c][tx * 4 + 3];
            *(ushort4*)(rwT + (size_t)(c0 + c) * 2048 + r0 + tx * 4) = v;
        }
    }
}

// ---------------------------------------------------------------------------
// transpose + cast: in[R,C] f32 -> out[C,R] bf16, 64x64 tiles (plan A rW)
// ---------------------------------------------------------------------------
__global__ __launch_bounds__(256)
void k_transpose(const float* __restrict__ in, u16* __restrict__ out, int R, int C)
{
    __shared__ __align__(16) u16 t[64][68];
    const int tid = threadIdx.x, tx = tid & 15, ty = tid >> 4;
    const int c0 = blockIdx.x * 64, r0 = blockIdx.y * 64;
#pragma unroll
    for (int i = 0; i < 4; i++) {
        int r = r0 + ty + i * 16;
        float4 v = *(const float4*)(in + (size_t)r * C + c0 + tx * 4);
        t[tx * 4 + 0][ty + i * 16] = f2b(v.x); t[tx * 4 + 1][ty + i * 16] = f2b(v.y);
        t[tx * 4 + 2][ty + i * 16] = f2b(v.z); t[tx * 4 + 3][ty + i * 16] = f2b(v.w);
    }
    __syncthreads();
#pragma unroll
    for (int i = 0; i < 4; i++) {
        int c = ty + i * 16;
        ushort4 v;
        v.x = t[c][tx * 4 + 0]; v.y = t[c][tx * 4 + 1];
        v.z = t[c][tx * 4 + 2]; v.w = t[c][tx * 4 + 3];
        *(ushort4*)(out + (size_t)(c0 + c) * R + r0 + tx * 4) = v;
    }
}

// ---------------------------------------------------------------------------
// 8-way activation blend
// ---------------------------------------------------------------------------
__device__ __forceinline__ float act_blend(float a,
    float w0, float w1, float w2, float w3,
    float w4, float w5, float w6, float w7)
{
    float sig = 1.f / (1.f + expf(-a));
    float elu = (a > 0.f) ? a : (expf(a) - 1.f);
    float th  = tanhf(a);
    float rel = fmaxf(a, 0.f);
    float sil = a * sig;
    float gel = a * 0.5f * (1.f + erff(a * 0.70710678118654752f));
    float sel = (a > 0.f) ? 1.0507009873554805f * a
                          : 1.0507009873554805f * 1.6732632423543772f * (expf(a) - 1.f);
    float sp  = (a > 20.f) ? a : log1pf(expf(a));
    float mish = a * tanhf(sp);
    return w0 * sig + w1 * elu + w2 * th + w3 * rel + w4 * sil + w5 * gel
         + w6 * sel + w7 * mish;
}

// ---------------------------------------------------------------------------
// GEMM-A (4-phase 256^2, split-K): P[z][n,u] partial = y@wmT^T over K-chunk z.
// grid (8, 8, 4), 512 thr, LDS 128 KiB -> 256 blocks, 1/CU.
// ---------------------------------------------------------------------------
__global__ __launch_bounds__(512, 2)
void k_gemm_a8(const u16* __restrict__ A, const u16* __restrict__ B,
               float* __restrict__ P)
{
    __shared__ __align__(16) char lds[131072];
    const int row0 = blockIdx.y * 256, col0 = blockIdx.x * 256;
    const u16* Ac = A + (size_t)blockIdx.z * 1024;
    const u16* Bc = B + (size_t)blockIdx.z * 1024;

    f32x4 acc[8][4];
    gemm256_core8(Ac, Bc, 16, 4096, row0, col0, lds, acc);

    float* Pz = P + (size_t)blockIdx.z * 2048 * 2048;
    const int tid = threadIdx.x, lane = tid & 63, wv = tid >> 6;
    const int wr = wv >> 2, wc = wv & 3, lr = lane & 15, kg = lane >> 4;
#pragma unroll
    for (int i = 0; i < 8; i++)
#pragma unroll
        for (int r = 0; r < 4; r++) {
            int n = row0 + wr * 128 + i * 16 + kg * 4 + r;
            size_t ob = (size_t)n * 2048;
#pragma unroll
            for (int j = 0; j < 4; j++)
                Pz[ob + col0 + wc * 64 + j * 16 + lr] = acc[i][j][r];
        }
}

// ---------------------------------------------------------------------------
// reduce 4 split-K partials + GEMM-A epilogue:
// blend[n,u] = blend8(relu((sum_s P[s][n,u] + gate[n]·b[u])*conn[u]*mask[u]))
// ---------------------------------------------------------------------------
__global__ __launch_bounds__(256)
void k_reduce_blend(const float* __restrict__ P, const float* __restrict__ gate,
                    const float* __restrict__ conn, const float* __restrict__ mask,
                    const float* __restrict__ wts, const float* __restrict__ bbias,
                    u16* __restrict__ blend)
{
    constexpr size_t SL = (size_t)2048 * 2048;
    const int n  = blockIdx.x;
    const int u0 = threadIdx.x * 8;
    const float* base = P + (size_t)n * 2048 + u0;

    float v[8];
#pragma unroll
    for (int h = 0; h < 2; h++) {
        float4 a = *(const float4*)(base + h * 4);
        float4 b = *(const float4*)(base + SL + h * 4);
        float4 c = *(const float4*)(base + 2 * SL + h * 4);
        float4 d = *(const float4*)(base + 3 * SL + h * 4);
        v[h * 4 + 0] = a.x + b.x + c.x + d.x;
        v[h * 4 + 1] = a.y + b.y + c.y + d.y;
        v[h * 4 + 2] = a.z + b.z + c.z + d.z;
        v[h * 4 + 3] = a.w + b.w + c.w + d.w;
    }
    float4 g = *(const float4*)(gate + n * 4);
    const float w0 = wts[0], w1 = wts[1], w2 = wts[2], w3 = wts[3];
    const float w4 = wts[4], w5 = wts[5], w6 = wts[6], w7 = wts[7];

    ushort4 o[2];
#pragma unroll
    for (int j = 0; j < 8; j++) {
        int u = u0 + j;
        float4 b4 = *(const float4*)(bbias + u * 4);
        float z = v[j] + g.x * b4.x + g.y * b4.y + g.z * b4.z + g.w * b4.w;
        float a = fmaxf(z * conn[u] * mask[u], 0.f);
        u16 r = f2b(act_blend(a, w0, w1, w2, w3, w4, w5, w6, w7));
        ((u16*)o)[j] = r;
    }
    *(ushort4*)(blend + (size_t)n * 2048 + u0)     = o[0];
    *(ushort4*)(blend + (size_t)n * 2048 + u0 + 4) = o[1];
}

// ---------------------------------------------------------------------------
// GEMM-B (4-phase 256^2): logits[n,m] = blend@read_W^T + read_b (bf16 out)
// grid (32, 8), 512 thr -> 256 blocks, 1/CU.
// ---------------------------------------------------------------------------
__global__ __launch_bounds__(512, 2)
void k_gemm_logits8(const u16* __restrict__ BL, const u16* __restrict__ RWT,
                    const float* __restrict__ rbias, u16* __restrict__ out)
{
    __shared__ __align__(16) char lds[131072];
    const int row0 = blockIdx.y * 256, col0 = blockIdx.x * 256;

    f32x4 acc[8][4];
    gemm256_core8(BL, RWT, 32, 2048, row0, col0, lds, acc);

    const int tid = threadIdx.x, lane = tid & 63, wv = tid >> 6;
    const int wr = wv >> 2, wc = wv & 3, lr = lane & 15, kg = lane >> 4;
    float rb[4]; int mm[4];
#pragma unroll
    for (int j = 0; j < 4; j++) {
        mm[j] = col0 + wc * 64 + j * 16 + lr;
        rb[j] = rbias[mm[j]];
    }
#pragma unroll
    for (int i = 0; i < 8; i++)
#pragma unroll
        for (int r = 0; r < 4; r++) {
            int n = row0 + wr * 128 + i * 16 + kg * 4 + r;
            size_t ob = (size_t)n * 8192;
#pragma unroll
            for (int j = 0; j < 4; j++)
                out[ob + mm[j]] = f2b(acc[i][j][r] + rb[j]);
        }
}

// ---------------------------------------------------------------------------
// k_post: fused softmax(logits) ∥ transpose(mem -> memT).
//   blocks 0-2047   : in-place row softmax over 8192 bf16
//   blocks 2048-4095: mem[8192,1024] f32 -> memT[1024,8192] bf16
// ---------------------------------------------------------------------------
__global__ __launch_bounds__(256)
void k_post(u16* __restrict__ buf, const float* __restrict__ mem,
            u16* __restrict__ memT)
{
    __shared__ __align__(16) char sh[64 * 68 * 2 + 64];
    const int bid = blockIdx.x;
    const int tid = threadIdx.x;

    if (bid < 2048) {
        float* red = (float*)sh;
        const int lane = tid & 63, wv = tid >> 6;
        u16* row = buf + (size_t)bid * 8192;
        float v[32];
        float mx = -1e30f;
#pragma unroll
        for (int s = 0; s < 8; s++) {
            ushort4 u4 = *(const ushort4*)(row + (s * 256 + tid) * 4);
            float a = b2f(u4.x), b = b2f(u4.y), c = b2f(u4.z), d = b2f(u4.w);
            v[s * 4 + 0] = a; v[s * 4 + 1] = b; v[s * 4 + 2] = c; v[s * 4 + 3] = d;
            mx = fmaxf(mx, fmaxf(fmaxf(a, b), fmaxf(c, d)));
        }
#pragma unroll
        for (int off = 32; off > 0; off >>= 1) mx = fmaxf(mx, __shfl_xor(mx, off));
        if (lane == 0) red[wv] = mx;
        __syncthreads();
        mx = fmaxf(fmaxf(red[0], red[1]), fmaxf(red[2], red[3]));
        float sum = 0.f;
#pragma unroll
        for (int k = 0; k < 32; k++) { v[k] = expf(v[k] - mx); sum += v[k]; }
#pragma unroll
        for (int off = 32; off > 0; off >>= 1) sum += __shfl_xor(sum, off);
        if (lane == 0) red[4 + wv] = sum;
        __syncthreads();
        float inv = 1.f / (red[4] + red[5] + red[6] + red[7]);
#pragma unroll
        for (int s = 0; s < 8; s++) {
            ushort4 o;
            o.x = f2b(v[s * 4 + 0] * inv); o.y = f2b(v[s * 4 + 1] * inv);
            o.z = f2b(v[s * 4 + 2] * inv); o.w = f2b(v[s * 4 + 3] * inv);
            *(ushort4*)(row + (s * 256 + tid) * 4) = o;
        }
    } else {
        typedef u16 row68[68];
        row68* t = (row68*)sh;
        const int b = bid - 2048;
        const int c0 = (b & 15) * 64, r0 = (b >> 4) * 64;   // C=1024, R=8192
        const int tx = tid & 15, ty = tid >> 4;
#pragma unroll
        for (int i = 0; i < 4; i++) {
            int r = r0 + ty + i * 16;
            float4 v = *(const float4*)(mem + (size_t)r * 1024 + c0 + tx * 4);
            t[tx * 4 + 0][ty + i * 16] = f2b(v.x); t[tx * 4 + 1][ty + i * 16] = f2b(v.y);
            t[tx * 4 + 2][ty + i * 16] = f2b(v.z); t[tx * 4 + 3][ty + i * 16] = f2b(v.w);
        }
        __syncthreads();
#pragma unroll
        for (int i = 0; i < 4; i++) {
            int c = ty + i * 16;
            ushort4 v;
            v.x = t[c][tx * 4 + 0]; v.y = t[c][tx * 4 + 1];
            v.z = t[c][tx * 4 + 2]; v.w = t[c][tx * 4 + 3];
            *(ushort4*)(memT + (size_t)(c0 + c) * 8192 + r0 + tx * 4) = v;
        }
    }
}

// ---------------------------------------------------------------------------
// GEMM-C plan B (4-phase 256^2, split-K=8): P[z][n,md] = attn @ memT^T chunk.
// grid (4, 8, 8), 512 thr -> 256 blocks, 1/CU. Kchunk=1024 (16 Ktiles).
// ---------------------------------------------------------------------------
__global__ __launch_bounds__(512, 2)
void k_gemm_c8(const u16* __restrict__ A, const u16* __restrict__ B,
               float* __restrict__ P)
{
    __shared__ __align__(16) char lds[131072];
    const int row0 = blockIdx.y * 256, col0 = blockIdx.x * 256;
    const u16* Ac = A + (size_t)blockIdx.z * 1024;
    const u16* Bc = B + (size_t)blockIdx.z * 1024;

    f32x4 acc[8][4];
    gemm256_core8(Ac, Bc, 16, 8192, row0, col0, lds, acc);

    float* Pz = P + (size_t)blockIdx.z * 2048 * 1024;
    const int tid = threadIdx.x, lane = tid & 63, wv = tid >> 6;
    const int wr = wv >> 2, wc = wv & 3, lr = lane & 15, kg = lane >> 4;
#pragma unroll
    for (int i = 0; i < 8; i++)
#pragma unroll
        for (int r = 0; r < 4; r++) {
            int n = row0 + wr * 128 + i * 16 + kg * 4 + r;
            size_t ob = (size_t)n * 1024;
#pragma unroll
            for (int j = 0; j < 4; j++)
                Pz[ob + col0 + wc * 64 + j * 16 + lr] = acc[i][j][r];
        }
}

// ---------------------------------------------------------------------------
// GEMM-C plan A fallback (2-phase 128^2 split-K, S=2)
// ---------------------------------------------------------------------------
template<int BM, int BN, int S, int NCOL>
__global__ __launch_bounds__(256, 4)
void k_gemm_partial(const u16* __restrict__ A, const u16* __restrict__ B,
                    int Kchunk, int ld, float* __restrict__ P)
{
    constexpr int MT = BM / 32, NT = BN / 32;
    __shared__ __align__(16) u16 smem[2 * (BM + BN) * 32 * S];

    const int nx = gridDim.x, ny = gridDim.y;
    const int f  = blockIdx.x + nx * blockIdx.y;
    const int ch = (nx * ny) >> 3;                 // chunk per XCD
    const int sw = (f & 7) * ch + (f >> 3);        // bijective (nwg%8==0)
    const int bx = sw % nx, by = sw / nx;
    const int row0 = by * BM, col0 = bx * BN;

    const u16* Ac = A + (size_t)blockIdx.z * Kchunk;
    const u16* Bc = B + (size_t)blockIdx.z * Kchunk;

    f32x4 acc[MT][NT];
    gemm_core_db<BM, BN, S>(Ac, Bc, Kchunk, ld, row0, col0, smem, acc);

    float* Pz = P + (size_t)blockIdx.z * 2048 * NCOL;
    const int tid = threadIdx.x, lane = tid & 63, wv = tid >> 6;
    const int wr = wv >> 1, wc = wv & 1, lr = lane & 15, kg = lane >> 4;
#pragma unroll
    for (int i = 0; i < MT; i++)
#pragma unroll
        for (int r = 0; r < 4; r++) {
            int n = row0 + wr * (BM / 2) + i * 16 + kg * 4 + r;
            size_t ob = (size_t)n * NCOL;
#pragma unroll
            for (int j = 0; j < NT; j++)
                Pz[ob + col0 + wc * (BN / 2) + j * 16 + lr] = acc[i][j][r];
        }
}

// ---------------------------------------------------------------------------
// reduce NSL split-K partials into final f32 output (GEMM-C tail)
// ---------------------------------------------------------------------------
template<int NSL>
__global__ __launch_bounds__(256)
void k_reduce_out(const float* __restrict__ P, float* __restrict__ out)
{
    constexpr size_t SL = (size_t)2048 * 1024;
    size_t i = ((size_t)blockIdx.x * 256 + threadIdx.x) * 4;
    float4 o = *(const float4*)(P + i);
#pragma unroll
    for (int s = 1; s < NSL; s++) {
        float4 p = *(const float4*)(P + s * SL + i);
        o.x += p.x; o.y += p.y; o.z += p.z; o.w += p.w;
    }
    *(float4*)(out + i) = o;
}

// sentinel: distinctive output if workspace is too small (absmax ~12345)
__global__ void k_fill(float* out, int n)
{
    int i = blockIdx.x * 256 + threadIdx.x;
    if (i < n) out[i] = 12345.f;
}

// ---------------------------------------------------------------------------
extern "C" void kernel_launch(void* const* d_in, const int* in_sizes, int n_in,
                              void* d_out, int out_size, void* d_ws, size_t ws_size,
                              hipStream_t stream)
{
    const float* x     = (const float*)d_in[0];
    const float* w     = (const float*)d_in[1];
    const float* delay = (const float*)d_in[2];
    const float* bb    = (const float*)d_in[3];
    const float* gW    = (const float*)d_in[4];
    const float* gb    = (const float*)d_in[5];
    const float* na    = (const float*)d_in[6];
    const float* cW1   = (const float*)d_in[7];
    const float* cb1   = (const float*)d_in[8];
    const float* cW2   = (const float*)d_in[9];
    const float* cb2   = (const float*)d_in[10];
    const float* mask  = (const float*)d_in[11];
    const float* actw  = (const float*)d_in[12];
    const float* rW    = (const float*)d_in[13];
    const float* rb    = (const float*)d_in[14];
    const float* mem   = (const float*)d_in[15];
    (void)in_sizes; (void)n_in;

    char* ws = (char*)d_ws;
    size_t off = 0;
    auto alloc = [&](size_t bytes) {
        size_t o = off; off += (bytes + 255) & ~(size_t)255; return o;
    };
    size_t o_wts   = alloc(9 * 4);
    size_t o_gate  = alloc(2048 * 4 * 4);
    size_t o_conn  = alloc(2048 * 4);
    size_t o_y     = alloc((size_t)2048 * 4096 * 2);   // y; later aliased as memT
    size_t o_wmT   = alloc((size_t)2048 * 4096 * 2);
    size_t o_blend = alloc((size_t)2048 * 2048 * 2);
    size_t o_rwT   = alloc((size_t)8192 * 2048 * 2);   // rwT (plan A: + partials)
    size_t o_log   = alloc((size_t)2048 * 8192 * 2);   // logits
    size_t base_off = off;

    if (base_off > ws_size) {   // loud, distinguishable failure mode
        k_fill<<<(out_size + 255) / 256, 256, 0, stream>>>((float*)d_out, out_size);
        return;
    }

    // plan B: dedicated 64MB partial pool (A-partials 4x16MB; C-partials 8x8MB)
    size_t o_pool = alloc((size_t)64 * 1024 * 1024);
    const bool planB = (off <= ws_size);

    float* wts   = (float*)(ws + o_wts);
    float* gate  = (float*)(ws + o_gate);
    float* conn  = (float*)(ws + o_conn);
    u16* y       = (u16*)(ws + o_y);
    u16* wmT     = (u16*)(ws + o_wmT);
    u16* blend   = (u16*)(ws + o_blend);
    u16* rwT     = (u16*)(ws + o_rwT);
    u16* logits  = (u16*)(ws + o_log);
    u16* memT    = y;   // y dead after GEMM-A; same size (16 MB)

    if (planB) {
        float* pool = (float*)(ws + o_pool);
        // prep: small ∥ gate+y ∥ wmT ∥ rW-transpose (1+512+1024+4096 blocks)
        k_prep<<<5633, 256, 0, stream>>>(na, cW1, cb1, cW2, cb2, actw, conn, wts,
                                         x, gW, gb, gate, y, w, delay, wmT,
                                         rW, rwT);
        k_gemm_a8<<<dim3(8, 8, 4), 512, 0, stream>>>(y, wmT, pool);
        k_reduce_blend<<<2048, 256, 0, stream>>>(pool, gate, conn, mask, wts, bb, blend);
        k_gemm_logits8<<<dim3(32, 8), 512, 0, stream>>>(blend, rwT, rb, logits);
        k_post<<<4096, 256, 0, stream>>>(logits, mem, memT);
        // GEMM-C: 256^2 core, split-K=8 (Kchunk=1024); partials reuse pool
        k_gemm_c8<<<dim3(4, 8, 8), 512, 0, stream>>>(logits, memT, pool);
        k_reduce_out<8><<<2048, 256, 0, stream>>>(pool, (float*)d_out);
    } else {
        // plan A — R15 schedule exactly (partials aliased into rwT+logits hole)
        float* pA = (float*)(ws + o_rwT);
        float* pC = (float*)(ws + o_rwT);
        k_prep<<<1537, 256, 0, stream>>>(na, cW1, cb1, cW2, cb2, actw, conn, wts,
                                         x, gW, gb, gate, y, w, delay, wmT,
                                         rW, rwT);
        k_gemm_a8<<<dim3(8, 8, 4), 512, 0, stream>>>(y, wmT, pA);
        k_reduce_blend<<<2048, 256, 0, stream>>>(pA, gate, conn, mask, wts, bb, blend);
        k_transpose<<<dim3(128, 32), 256, 0, stream>>>(rW, rwT, 2048, 8192);
        k_gemm_logits8<<<dim3(32, 8), 512, 0, stream>>>(blend, rwT, rb, logits);
        k_post<<<4096, 256, 0, stream>>>(logits, mem, memT);
        k_gemm_partial<128, 128, 2, 1024><<<dim3(8, 16, 4), 256, 0, stream>>>(
            logits, memT, 2048, 8192, pC);
        k_reduce_out<4><<<2048, 256, 0, stream>>>(pC, (float*)d_out);
    }
}